// Round 12
// baseline (479.429 us; speedup 1.0000x reference)
//
#include <hip/hip_runtime.h>
#include <hip/hip_bf16.h>
#include <math.h>

#define NN 50000
#define EE 800000
#define MPAD 50048          // 64-aligned row pad for MFMA GEMMs

// ---------- workspace layout (offsets in floats) ----------
#define OFF_QQBF   0ull          // MPAD*512 bf16 (lane-major permuted)
#define OFF_KVBF   12900000ull   // MPAD*512 bf16 (lane-major permuted)
#define OFF_AGGBF  25900000ull   // MPAD*512 bf16 (linear)
#define OFF_MSGBF  45300000ull   // MPAD*128 bf16 (linear)
#define OFF_INT    48600000ull   // ints: 4N+130+2E
#define OFF_WCATQ  50500000ull   // 128*512 fp32
#define OFF_WCATKV 50600000ull
#define OFF_WBIG   50700000ull   // 512*128 fp32
#define OFF_WGRU   50800000ull   // 256*512 fp32
#define OFF_BCATQ  51000000ull   // 512
#define OFF_BCATKV 51001000ull   // 512
#define OFF_BGRU   51002000ull   // 512
#define OFF_PQ     51010000ull   // packed bf16
#define OFF_PKV    51050000ull
#define OFF_PBIG   51090000ull
#define OFF_PGRU   51130000ull   // 131072 shorts
#define OFF_X0BF   51200000ull   // MPAD*128 bf16 (linear)
// end ~54.41M floats = 218 MB

typedef short bf16x8 __attribute__((ext_vector_type(8)));
typedef float f32x4 __attribute__((ext_vector_type(4)));
typedef float fv4 __attribute__((ext_vector_type(4)));
typedef unsigned short u16x8 __attribute__((ext_vector_type(8)));

__device__ inline unsigned short f2bf(float f) {   // round-to-nearest-even
  unsigned u = __float_as_uint(f);
  return (unsigned short)((u + 0x7FFFu + ((u >> 16) & 1u)) >> 16);
}
__device__ inline float bf2f(unsigned short u) {
  return __uint_as_float((unsigned)u << 16);
}
__device__ inline float4 bf2f4_lo(u16x8 u) {
  float4 r;
  r.x = bf2f(u[0]); r.y = bf2f(u[1]); r.z = bf2f(u[2]); r.w = bf2f(u[3]);
  return r;
}
__device__ inline float4 bf2f4_hi(u16x8 u) {
  float4 r;
  r.x = bf2f(u[4]); r.y = bf2f(u[5]); r.z = bf2f(u[6]); r.w = bf2f(u[7]);
  return r;
}

// ---------- K1: weight prep + sort-counter zeroing: 870 blocks x 256 ----------
__global__ void prep_all(const float* __restrict__ Wq, const float* __restrict__ bq,
                         const float* __restrict__ Wk, const float* __restrict__ bk,
                         const float* __restrict__ Wv, const float* __restrict__ bv,
                         const float* __restrict__ Wo,
                         const float* __restrict__ W_ih, const float* __restrict__ b_ih,
                         const float* __restrict__ W_hh, const float* __restrict__ b_hh,
                         float* __restrict__ WcatQ, float* __restrict__ bcatQ,
                         float* __restrict__ WcatKV, float* __restrict__ bcatKV,
                         float* __restrict__ Wbig, float* __restrict__ WgruCat,
                         float* __restrict__ bgru, int* __restrict__ zint) {
  const int bid = blockIdx.x, j = threadIdx.x;
  if (bid < 129) {                       // Wqk = Wq @ Wk_h^T per head (+ bias row)
    int c0 = bid, h = j >> 7, c = j & 127;
    const float* wkrow = Wk + (size_t)c * 256 + h * 128;
    float acc = 0.f;
    if (c0 < 128) {
      const float* wqrow = Wq + (size_t)c0 * 256 + h * 128;
      for (int d = 0; d < 128; d++) acc += wqrow[d] * wkrow[d];
      WcatQ[c0 * 512 + 256 + j] = acc;
    } else {
      for (int d = 0; d < 128; d++) acc += bq[h * 128 + d] * wkrow[d];
      bcatQ[256 + j] = acc;
    }
  } else if (bid < 257) {                // pack Wq / Wk2 / Wv2 + biases
    int r = bid - 129;
    WcatQ[r * 512 + j] = Wq[r * 256 + j];
    WcatKV[r * 512 + j] = Wk[(size_t)(128 + r) * 256 + j];
    WcatKV[r * 512 + 256 + j] = Wv[(size_t)(128 + r) * 256 + j];
    if (r == 0) {
      bcatQ[j] = bq[j];
      bcatKV[j] = bk[j];
      bcatKV[256 + j] = bv[j];
    }
  } else if (bid < 513) {                // Wbig (2 rows per block)
    int r = (bid - 257) * 2 + (j >> 7), jj = j & 127;
    if (r < 256) {
      int h = r >> 7, c = r & 127;
      float acc = 0.f;
      for (int d = 0; d < 128; d++)
        acc += Wv[(size_t)c * 256 + h * 128 + d] * Wo[(size_t)(h * 128 + d) * 128 + jj];
      Wbig[r * 128 + jj] = acc;
    } else {
      Wbig[r * 128 + jj] = Wo[(size_t)(r - 256) * 128 + jj];
    }
  } else if (bid < 769) {                // WgruCat row r: [x0|msg] -> [rsum|zsum|i_n|h_n]
    int r = bid - 513;
    for (int c = j; c < 512; c += 256) {
      float v;
      if (r < 128) v = (c < 384) ? W_ih[(size_t)r * 384 + c] : 0.f;
      else {
        int rm = r - 128;
        v = (c < 256) ? W_hh[(size_t)rm * 384 + c]
                      : (c < 384 ? 0.f : W_hh[(size_t)rm * 384 + 256 + (c - 384)]);
      }
      WgruCat[(size_t)r * 512 + c] = v;
    }
  } else if (bid == 769) {               // bgru
    bgru[j] = b_ih[j] + b_hh[j];                      // rsum/zsum biases (j<256)
    int c1 = j + 256;
    bgru[c1] = (c1 < 384) ? b_ih[c1] : b_hh[c1 - 128]; // i_n / h_n biases
  } else {                               // bid 770..869: zero cnt+cursor (2N ints)
    int g = ((bid - 770) * 256 + j) * 4;
    if (g < 2 * NN) *reinterpret_cast<int4*>(zint + g) = make_int4(0, 0, 0, 0);
  }
}

// ---------- K2: weight pack (blocks 0..39) + edge histogram (40..821) ----------
__global__ __launch_bounds__(1024) void pack_hist(
    const float* __restrict__ WcatQ, const float* __restrict__ WcatKV,
    const float* __restrict__ Wbig, const float* __restrict__ WgruCat,
    unsigned short* __restrict__ pQ, unsigned short* __restrict__ pKV,
    unsigned short* __restrict__ pBig, unsigned short* __restrict__ pGRU,
    const int* __restrict__ edges, int* __restrict__ cnt) {
  const int bid = blockIdx.x, tid = threadIdx.x;
  if (bid < 40) {
    int idx = bid * 1024 + tid;          // 0..40959
    const float* W; unsigned short* P; int KK, Nc;
    if (idx < 8192)       { W = WcatQ;   P = pQ;   KK = 128; Nc = 512; }
    else if (idx < 16384) { W = WcatKV;  P = pKV;  KK = 128; Nc = 512; idx -= 8192; }
    else if (idx < 24576) { W = Wbig;    P = pBig; KK = 512; Nc = 128; idx -= 16384; }
    else                  { W = WgruCat; P = pGRU; KK = 256; Nc = 512; idx -= 24576; }
    int nbs = Nc >> 4;
    int lane = idx & 63;
    int pair = idx >> 6;
    int kb = pair / nbs, nb = pair - kb * nbs;
    int kbase = kb * 32 + (lane >> 4) * 8;
    int col = nb * 16 + (lane & 15);
    unsigned short o[8];
#pragma unroll
    for (int j = 0; j < 8; ++j) o[j] = f2bf(W[(size_t)(kbase + j) * Nc + col]);
    *reinterpret_cast<bf16x8*>(P + (size_t)idx * 8) = *reinterpret_cast<bf16x8*>(o);
  } else {
    int e = (bid - 40) * 1024 + tid;
    if (e < EE) atomicAdd(&cnt[edges[EE + e]], 1);
  }
}

// ---------- K3: per-chunk inclusive scan (49 blocks x 1024, coalesced) ----------
__global__ __launch_bounds__(1024) void scan_partial(const int* __restrict__ cnt,
                                                     int* __restrict__ basep,
                                                     int* __restrict__ bsum) {
  __shared__ int sd[1024];
  int t = threadIdx.x, g = blockIdx.x * 1024 + t;
  int v = (g < NN) ? cnt[g] : 0;
  sd[t] = v;
  __syncthreads();
  for (int d = 1; d < 1024; d <<= 1) {
    int add = (t >= d) ? sd[t - d] : 0;
    __syncthreads();
    sd[t] += add;
    __syncthreads();
  }
  if (g < NN) basep[g] = sd[t] - v;
  if (t == 1023) bsum[blockIdx.x] = sd[1023];
}

// ---------- K4: finalize scan — per-block redundant bsum prefix + add ----------
__global__ __launch_bounds__(1024) void scan_final(const int* __restrict__ bsum,
                                                   const int* __restrict__ basep,
                                                   int* __restrict__ base) {
  __shared__ int s_off;
  const int bid = blockIdx.x, tid = threadIdx.x;
  if (tid < 64) {
    int v = (tid < 49) ? bsum[tid] : 0;
    int incl = v;
#pragma unroll
    for (int off = 1; off < 64; off <<= 1) {
      int o = __shfl_up(incl, off);
      if (tid >= off) incl += o;
    }
    int ex = (bid == 0) ? 0 : __shfl(incl, bid - 1);
    if (tid == 0) s_off = ex;
  }
  __syncthreads();
  int g = bid * 1024 + tid;
  if (g < NN) base[g] = basep[g] + s_off;
  if (bid == 48 && tid == 0) base[NN] = EE;
}

// ---------- MFMA bf16 GEMM body; OUT: 1=bf16, 2=f32+bf16; AF32: A is fp32 ----------
// PERM: lane-major permute of Cbf columns (c -> (c&127)/4*16 + (c>>7)*4 + (c&3))
template <int OUT, int AF32, int NF, int EMITA, int PERM>
__device__ __forceinline__ void gemm_body(
    int bx, int by, const void* __restrict__ Av, const unsigned short* __restrict__ Wp,
    const float* __restrict__ bias, float* __restrict__ C,
    unsigned short* __restrict__ Cbf, unsigned short* __restrict__ Abf,
    int M, int Arows, int K, int Nc) {
  const int wid = threadIdx.x >> 6, lane = threadIdx.x & 63;
  const int m0 = by * 64 + wid * 16;
  const int nb0 = bx * NF;
  const int nbs = Nc >> 4;
  const int row = m0 + (lane & 15);
  const int arow = min(row, Arows - 1);
  const int kq = lane >> 4;
  f32x4 acc[NF];
#pragma unroll
  for (int nf = 0; nf < NF; ++nf) acc[nf] = 0.f;
  const int nkb = K >> 5;
  for (int kb = 0; kb < nkb; ++kb) {
    bf16x8 a;
    if (AF32) {
      const float* ap = (const float*)Av + (size_t)arow * K + kb * 32 + kq * 8;
      const float4 f0 = *(const float4*)ap;
      const float4 f1 = *(const float4*)(ap + 4);
      unsigned short t[8] = {f2bf(f0.x), f2bf(f0.y), f2bf(f0.z), f2bf(f0.w),
                             f2bf(f1.x), f2bf(f1.y), f2bf(f1.z), f2bf(f1.w)};
      a = *reinterpret_cast<bf16x8*>(t);
      if (EMITA) {
        if (bx == 0)
          *reinterpret_cast<bf16x8*>(Abf + (size_t)arow * K + kb * 32 + kq * 8) = a;
      }
    } else {
      a = *reinterpret_cast<const bf16x8*>(
          (const unsigned short*)Av + (size_t)arow * K + kb * 32 + kq * 8);
    }
#pragma unroll
    for (int nf = 0; nf < NF; ++nf) {
      bf16x8 b = *reinterpret_cast<const bf16x8*>(
          Wp + ((size_t)(kb * nbs + nb0 + nf) * 64 + lane) * 8);
      acc[nf] = __builtin_amdgcn_mfma_f32_16x16x32_bf16(a, b, acc[nf], 0, 0, 0);
    }
  }
  const int crow0 = m0 + (lane >> 4) * 4;
  const int ccol = lane & 15;
#pragma unroll
  for (int nf = 0; nf < NF; ++nf) {
    const float bv = bias[(nb0 + nf) * 16 + ccol];
#pragma unroll
    for (int r = 0; r < 4; ++r) {
      float v = acc[nf][r] + bv;
      float vp = __shfl_xor(v, 1);
      const int rr = crow0 + r;
      if (rr < M) {
        if (OUT == 2)
          C[(size_t)rr * Nc + (nb0 + nf) * 16 + ccol] = v;
        if (!(lane & 1)) {
          int c = (nb0 + nf) * 16 + (ccol & ~1);
          int dc;
          if (PERM) {
            int rg = c >> 7, oo = c & 127;
            dc = (oo >> 2) * 16 + rg * 4 + (oo & 3);
          } else {
            dc = c;
          }
          ushort2 o2;
          o2.x = f2bf(v);
          o2.y = f2bf(vp);
          *reinterpret_cast<ushort2*>(Cbf + (size_t)rr * Nc + dc) = o2;
        }
      }
    }
  }
}

template <int OUT, int AF32, int NF, int EMITA, int PERM>
__global__ __launch_bounds__(256) void gemm_mfma(
    const void* __restrict__ Av, const unsigned short* __restrict__ Wp,
    const float* __restrict__ bias, float* __restrict__ C,
    unsigned short* __restrict__ Cbf, unsigned short* __restrict__ Abf,
    int M, int Arows, int K, int Nc) {
  gemm_body<OUT, AF32, NF, EMITA, PERM>(blockIdx.x, blockIdx.y, Av, Wp, bias, C,
                                        Cbf, Abf, M, Arows, K, Nc);
}

// ---------- K5: scatter (blocks 0..3124) + projQQ (..6252) + projKV (..9380) ----------
__global__ __launch_bounds__(256) void scatter_proj(
    const int* __restrict__ edges, const int* __restrict__ base,
    int* __restrict__ cursor, int2* __restrict__ epairs,
    const float* __restrict__ x0, const float* __restrict__ x1,
    const unsigned short* __restrict__ pQ, const unsigned short* __restrict__ pKV,
    const float* __restrict__ bcatQ, const float* __restrict__ bcatKV,
    unsigned short* __restrict__ QQbf, unsigned short* __restrict__ KVbf,
    unsigned short* __restrict__ x0bf) {
  const int bid = blockIdx.x;
  if (bid < 3125) {
    int e = bid * 256 + threadIdx.x;
    int s = edges[e];
    int d = edges[EE + e];
    int pos = base[d] + atomicAdd(&cursor[d], 1);
    epairs[pos] = make_int2(e, s);
  } else if (bid < 6253) {
    int pb = bid - 3125;
    gemm_body<1, 1, 8, 1, 1>(pb & 3, pb >> 2, x0, pQ, bcatQ, nullptr, QQbf, x0bf,
                             NN, NN, 128, 512);
  } else {
    int pb = bid - 6253;
    gemm_body<1, 1, 8, 0, 1>(pb & 3, pb >> 2, x1, pKV, bcatKV, nullptr, KVbf,
                             nullptr, NN, NN, 128, 512);
  }
}

// ---------- K6: fused attention: one wave per node, half-wave per edge ----------
// QQbf/KVbf lane-major permuted: lane l's 16 elems contiguous at 16*l;
// per edge: 2x16B loads instead of 4x8B (halved gather request count).
__global__ __launch_bounds__(256) void attn_wave_kernel(
    const float* __restrict__ edge_attr, const unsigned short* __restrict__ QQbf,
    const unsigned short* __restrict__ KVbf, const int* __restrict__ base,
    const int2* __restrict__ epairs, unsigned short* __restrict__ aggbf) {
  const int wid = threadIdx.x >> 6, lane = threadIdx.x & 63;
  const int n = blockIdx.x * 4 + wid;
  if (n >= NN) return;
  const int hh = lane >> 5;            // which edge of the pair
  const int l = lane & 31;             // elem group: 4 elems per 128-block
  const unsigned short* qp = QQbf + (size_t)n * 512 + 16 * l;
  const u16x8 qa = *(const u16x8*)(qp);        // q0 | q1
  const u16x8 qb = *(const u16x8*)(qp + 8);    // w0 | w1
  const float4 q0 = bf2f4_lo(qa), q1 = bf2f4_hi(qa);
  const float4 w0 = bf2f4_lo(qb), w1 = bf2f4_hi(qb);
  const int beg = base[n], end = base[n + 1];
  float s0 = 0.f, s1 = 0.f;
  float4 ae0 = {0.f, 0.f, 0.f, 0.f}, ae1 = {0.f, 0.f, 0.f, 0.f};
  float4 av0 = {0.f, 0.f, 0.f, 0.f}, av1 = {0.f, 0.f, 0.f, 0.f};
  const float SC = 0.08838834764831845f;
  for (int p = beg; p < end; p += 2) {
    const int pe = min(p + hh, end - 1);
    const bool act = (p + hh < end);
    const int2 es = epairs[pe];
    const fv4 eav = __builtin_nontemporal_load(
        (const fv4*)(edge_attr + (size_t)es.x * 128 + 4 * l));
    const float4 ea = {eav.x, eav.y, eav.z, eav.w};
    const unsigned short* kp = KVbf + (size_t)es.y * 512 + 16 * l;
    const u16x8 ka = *(const u16x8*)(kp);      // k0 | k1
    const u16x8 kb = *(const u16x8*)(kp + 8);  // v0 | v1
    const float4 k0 = bf2f4_lo(ka), k1 = bf2f4_hi(ka);
    const float4 v0 = bf2f4_lo(kb), v1 = bf2f4_hi(kb);
    float p0 = ea.x * w0.x + ea.y * w0.y + ea.z * w0.z + ea.w * w0.w
             + q0.x * k0.x + q0.y * k0.y + q0.z * k0.z + q0.w * k0.w;
    float p1 = ea.x * w1.x + ea.y * w1.y + ea.z * w1.z + ea.w * w1.w
             + q1.x * k1.x + q1.y * k1.y + q1.z * k1.z + q1.w * k1.w;
#pragma unroll
    for (int off = 16; off; off >>= 1) {
      p0 += __shfl_xor(p0, off);
      p1 += __shfl_xor(p1, off);
    }
    float a0 = p0 * SC; a0 = (a0 < 0.f) ? 0.2f * a0 : a0;
    float a1 = p1 * SC; a1 = (a1 < 0.f) ? 0.2f * a1 : a1;
    const float x0 = act ? __expf(a0) : 0.f;
    const float x1 = act ? __expf(a1) : 0.f;
    s0 += x0; s1 += x1;
    ae0.x += x0 * ea.x; ae0.y += x0 * ea.y; ae0.z += x0 * ea.z; ae0.w += x0 * ea.w;
    ae1.x += x1 * ea.x; ae1.y += x1 * ea.y; ae1.z += x1 * ea.z; ae1.w += x1 * ea.w;
    av0.x += x0 * v0.x; av0.y += x0 * v0.y; av0.z += x0 * v0.z; av0.w += x0 * v0.w;
    av1.x += x1 * v1.x; av1.y += x1 * v1.y; av1.z += x1 * v1.z; av1.w += x1 * v1.w;
  }
  // combine the two half-wave accumulators
  s0 += __shfl_xor(s0, 32); s1 += __shfl_xor(s1, 32);
  ae0.x += __shfl_xor(ae0.x, 32); ae0.y += __shfl_xor(ae0.y, 32);
  ae0.z += __shfl_xor(ae0.z, 32); ae0.w += __shfl_xor(ae0.w, 32);
  ae1.x += __shfl_xor(ae1.x, 32); ae1.y += __shfl_xor(ae1.y, 32);
  ae1.z += __shfl_xor(ae1.z, 32); ae1.w += __shfl_xor(ae1.w, 32);
  av0.x += __shfl_xor(av0.x, 32); av0.y += __shfl_xor(av0.y, 32);
  av0.z += __shfl_xor(av0.z, 32); av0.w += __shfl_xor(av0.w, 32);
  av1.x += __shfl_xor(av1.x, 32); av1.y += __shfl_xor(av1.y, 32);
  av1.z += __shfl_xor(av1.z, 32); av1.w += __shfl_xor(av1.w, 32);
  const float i0 = 1.f / (s0 + 1e-16f), i1 = 1.f / (s1 + 1e-16f);
  if (hh == 0) {
    // aggbf stays LINEAR (consumed as GEMM A-matrix)
    unsigned short* op = aggbf + (size_t)n * 512 + 4 * l;
    ushort4 o;
    o.x = f2bf(ae0.x * i0); o.y = f2bf(ae0.y * i0);
    o.z = f2bf(ae0.z * i0); o.w = f2bf(ae0.w * i0);
    *(ushort4*)op = o;
    o.x = f2bf(ae1.x * i1); o.y = f2bf(ae1.y * i1);
    o.z = f2bf(ae1.z * i1); o.w = f2bf(ae1.w * i1);
    *(ushort4*)(op + 128) = o;
    o.x = f2bf(av0.x * i0); o.y = f2bf(av0.y * i0);
    o.z = f2bf(av0.z * i0); o.w = f2bf(av0.w * i0);
    *(ushort4*)(op + 256) = o;
    o.x = f2bf(av1.x * i1); o.y = f2bf(av1.y * i1);
    o.z = f2bf(av1.z * i1); o.w = f2bf(av1.w * i1);
    *(ushort4*)(op + 384) = o;
  }
}

// ---------- K8: fused GRU: [x0|msg] @ WgruCat -> gates -> out ----------
__global__ __launch_bounds__(256) void gru_fused(
    const unsigned short* __restrict__ x0bf, const unsigned short* __restrict__ msgbf,
    const unsigned short* __restrict__ pGRU, const float* __restrict__ bgru,
    float* __restrict__ out) {
  const int wid = threadIdx.x >> 6, lane = threadIdx.x & 63;
  const int m0 = blockIdx.y * 64 + wid * 16;
  const int xq = blockIdx.x;           // output-dim quarter: d in [xq*32, xq*32+32)
  const int row = m0 + (lane & 15);
  const int ar = min(row, NN - 1);
  const int kq = lane >> 4;
  f32x4 acc[4][2];
#pragma unroll
  for (int g = 0; g < 4; ++g)
#pragma unroll
    for (int f = 0; f < 2; ++f) acc[g][f] = 0.f;
  for (int kb = 0; kb < 8; ++kb) {
    bf16x8 a;
    if (kb < 4) {
      a = *reinterpret_cast<const bf16x8*>(x0bf + (size_t)ar * 128 +
                                           kb * 32 + kq * 8);
    } else {
      a = *reinterpret_cast<const bf16x8*>(msgbf + (size_t)ar * 128 +
                                           (kb - 4) * 32 + kq * 8);
    }
#pragma unroll
    for (int g = 0; g < 4; ++g)
#pragma unroll
      for (int f = 0; f < 2; ++f) {
        const int nf = g * 8 + xq * 2 + f;
        bf16x8 b = *reinterpret_cast<const bf16x8*>(
            pGRU + ((size_t)(kb * 32 + nf) * 64 + lane) * 8);
        acc[g][f] = __builtin_amdgcn_mfma_f32_16x16x32_bf16(a, b, acc[g][f], 0, 0, 0);
      }
  }
  const int crow0 = m0 + (lane >> 4) * 4;
  const int ccol = lane & 15;
#pragma unroll
  for (int f = 0; f < 2; ++f) {
    const int d = xq * 32 + f * 16 + ccol;
    const float brs = bgru[d], bzs = bgru[128 + d];
    const float bin = bgru[256 + d], bhn = bgru[384 + d];
#pragma unroll
    for (int r = 0; r < 4; ++r) {
      const int rr = crow0 + r;
      if (rr < NN) {
        const float rs = acc[0][f][r] + brs;
        const float zs = acc[1][f][r] + bzs;
        const float iv = acc[2][f][r] + bin;
        const float hv = acc[3][f][r] + bhn;
        const float rg = 1.f / (1.f + __expf(-rs));
        const float zg = 1.f / (1.f + __expf(-zs));
        const float ng = tanhf(iv + rg * hv);
        const float h = bf2f(msgbf[(size_t)rr * 128 + d]);
        out[(size_t)rr * 128 + d] = (1.f - zg) * ng + zg * h;
      }
    }
  }
}

extern "C" void kernel_launch(void* const* d_in, const int* in_sizes, int n_in,
                              void* d_out, int out_size, void* d_ws, size_t ws_size,
                              hipStream_t stream) {
  const float* x0 = (const float*)d_in[0];
  const float* x1 = (const float*)d_in[1];
  const float* edge_attr = (const float*)d_in[2];
  const int* edges = (const int*)d_in[3];
  const float* Wq = (const float*)d_in[5];
  const float* bq = (const float*)d_in[6];
  const float* Wk = (const float*)d_in[7];
  const float* bk = (const float*)d_in[8];
  const float* Wv = (const float*)d_in[9];
  const float* bv = (const float*)d_in[10];
  const float* Wo = (const float*)d_in[11];
  const float* bo = (const float*)d_in[12];
  const float* W_ih = (const float*)d_in[13];
  const float* b_ih = (const float*)d_in[14];
  const float* W_hh = (const float*)d_in[15];
  const float* b_hh = (const float*)d_in[16];
  float* out = (float*)d_out;
  float* wsf = (float*)d_ws;

  unsigned short* QQbf  = (unsigned short*)(wsf + OFF_QQBF);
  unsigned short* KVbf  = (unsigned short*)(wsf + OFF_KVBF);
  unsigned short* aggbf = (unsigned short*)(wsf + OFF_AGGBF);
  unsigned short* msgbf = (unsigned short*)(wsf + OFF_MSGBF);
  unsigned short* x0bf  = (unsigned short*)(wsf + OFF_X0BF);
  int* ip    = (int*)(wsf + OFF_INT);
  int* cntb  = ip;                       // N
  int* curb  = ip + NN;                  // N
  int* bpart = ip + 2 * NN;              // N
  int* baseb = ip + 3 * NN;              // N+1
  int* bsumb = ip + 4 * NN + 1;          // 64
  int2* epairs = (int2*)(ip + 4 * NN + 130);   // 2E ints, 8B aligned
  float* WcatQ  = wsf + OFF_WCATQ;
  float* WcatKV = wsf + OFF_WCATKV;
  float* Wbigb  = wsf + OFF_WBIG;
  float* WgruC  = wsf + OFF_WGRU;
  float* bcatQ  = wsf + OFF_BCATQ;
  float* bcatKV = wsf + OFF_BCATKV;
  float* bgru   = wsf + OFF_BGRU;
  unsigned short* pQ   = (unsigned short*)(wsf + OFF_PQ);
  unsigned short* pKV  = (unsigned short*)(wsf + OFF_PKV);
  unsigned short* pBig = (unsigned short*)(wsf + OFF_PBIG);
  unsigned short* pGRU = (unsigned short*)(wsf + OFF_PGRU);

  // K1: weight prep + zero sort counters
  prep_all<<<870, 256, 0, stream>>>(Wq, bq, Wk, bk, Wv, bv, Wo, W_ih, b_ih,
                                    W_hh, b_hh, WcatQ, bcatQ, WcatKV, bcatKV,
                                    Wbigb, WgruC, bgru, ip);
  // K2: pack weights + histogram
  pack_hist<<<822, 1024, 0, stream>>>(WcatQ, WcatKV, Wbigb, WgruC,
                                      pQ, pKV, pBig, pGRU, edges, cntb);
  // K3/K4: two-level coalesced scan
  scan_partial<<<49, 1024, 0, stream>>>(cntb, bpart, bsumb);
  scan_final<<<49, 1024, 0, stream>>>(bsumb, bpart, baseb);
  // K5: scatter + both projection GEMMs (lane-major permuted outputs)
  scatter_proj<<<9381, 256, 0, stream>>>(edges, baseb, curb, epairs,
                                         x0, x1, pQ, pKV, bcatQ, bcatKV,
                                         QQbf, KVbf, x0bf);
  // K6: fused attention
  attn_wave_kernel<<<(NN + 3) / 4, 256, 0, stream>>>(edge_attr, QQbf, KVbf,
                                                     baseb, epairs, aggbf);
  // K7: msg = aggbf @ pBig + bo (bf16 out, linear)
  gemm_mfma<1, 0, 4, 0, 0><<<dim3(2, MPAD / 64), 256, 0, stream>>>(
      aggbf, pBig, bo, nullptr, msgbf, nullptr, NN, NN, 512, 128);
  // K8: fused GRU -> out
  gru_fused<<<dim3(4, MPAD / 64), 256, 0, stream>>>(x0bf, msgbf, pGRU, bgru, out);
}

// Round 13
// 441.378 us; speedup vs baseline: 1.0862x; 1.0862x over previous
//
#include <hip/hip_runtime.h>
#include <hip/hip_bf16.h>
#include <math.h>

#define NN 50000
#define EE 800000
#define MPAD 50048          // 64-aligned row pad for MFMA GEMMs

// ---------- workspace layout (offsets in floats) ----------
#define OFF_QQBF   0ull          // MPAD*512 bf16 = 12,812,288 fl
#define OFF_KVBF   12900000ull   // MPAD*512 bf16
#define OFF_AGGBF  25900000ull   // MPAD*512 bf16
#define OFF_MSGBF  45300000ull   // MPAD*128 bf16 = 3,203,072 fl
#define OFF_INT    48600000ull   // ints: 4N+130+2E = 1,800,130
#define OFF_WCATQ  50500000ull   // 128*512 fp32
#define OFF_WCATKV 50600000ull
#define OFF_WBIG   50700000ull   // 512*128 fp32
#define OFF_WGRU   50800000ull   // 256*512 fp32
#define OFF_BCATQ  51000000ull   // 512
#define OFF_BCATKV 51001000ull   // 512
#define OFF_BGRU   51002000ull   // 512
#define OFF_PQ     51010000ull   // packed bf16
#define OFF_PKV    51050000ull
#define OFF_PBIG   51090000ull
#define OFF_PGRU   51130000ull   // 131072 shorts
#define OFF_X0BF   51200000ull   // MPAD*128 bf16 = 3,203,072 fl
// end ~54.41M floats = 218 MB

typedef short bf16x8 __attribute__((ext_vector_type(8)));
typedef float f32x4 __attribute__((ext_vector_type(4)));
typedef float fv4 __attribute__((ext_vector_type(4)));    // native vec for nontemporal

__device__ inline unsigned short f2bf(float f) {   // round-to-nearest-even
  unsigned u = __float_as_uint(f);
  return (unsigned short)((u + 0x7FFFu + ((u >> 16) & 1u)) >> 16);
}
__device__ inline float bf2f(unsigned short u) {
  return __uint_as_float((unsigned)u << 16);
}
__device__ inline float4 bf2f4(ushort4 u) {
  float4 r;
  r.x = bf2f(u.x); r.y = bf2f(u.y); r.z = bf2f(u.z); r.w = bf2f(u.w);
  return r;
}

// ---------- K1: weight prep + sort-counter zeroing: 870 blocks x 256 ----------
__global__ void prep_all(const float* __restrict__ Wq, const float* __restrict__ bq,
                         const float* __restrict__ Wk, const float* __restrict__ bk,
                         const float* __restrict__ Wv, const float* __restrict__ bv,
                         const float* __restrict__ Wo,
                         const float* __restrict__ W_ih, const float* __restrict__ b_ih,
                         const float* __restrict__ W_hh, const float* __restrict__ b_hh,
                         float* __restrict__ WcatQ, float* __restrict__ bcatQ,
                         float* __restrict__ WcatKV, float* __restrict__ bcatKV,
                         float* __restrict__ Wbig, float* __restrict__ WgruCat,
                         float* __restrict__ bgru, int* __restrict__ zint) {
  const int bid = blockIdx.x, j = threadIdx.x;
  if (bid < 129) {                       // Wqk = Wq @ Wk_h^T per head (+ bias row)
    int c0 = bid, h = j >> 7, c = j & 127;
    const float* wkrow = Wk + (size_t)c * 256 + h * 128;
    float acc = 0.f;
    if (c0 < 128) {
      const float* wqrow = Wq + (size_t)c0 * 256 + h * 128;
      for (int d = 0; d < 128; d++) acc += wqrow[d] * wkrow[d];
      WcatQ[c0 * 512 + 256 + j] = acc;
    } else {
      for (int d = 0; d < 128; d++) acc += bq[h * 128 + d] * wkrow[d];
      bcatQ[256 + j] = acc;
    }
  } else if (bid < 257) {                // pack Wq / Wk2 / Wv2 + biases
    int r = bid - 129;
    WcatQ[r * 512 + j] = Wq[r * 256 + j];
    WcatKV[r * 512 + j] = Wk[(size_t)(128 + r) * 256 + j];
    WcatKV[r * 512 + 256 + j] = Wv[(size_t)(128 + r) * 256 + j];
    if (r == 0) {
      bcatQ[j] = bq[j];
      bcatKV[j] = bk[j];
      bcatKV[256 + j] = bv[j];
    }
  } else if (bid < 513) {                // Wbig (2 rows per block)
    int r = (bid - 257) * 2 + (j >> 7), jj = j & 127;
    if (r < 256) {
      int h = r >> 7, c = r & 127;
      float acc = 0.f;
      for (int d = 0; d < 128; d++)
        acc += Wv[(size_t)c * 256 + h * 128 + d] * Wo[(size_t)(h * 128 + d) * 128 + jj];
      Wbig[r * 128 + jj] = acc;
    } else {
      Wbig[r * 128 + jj] = Wo[(size_t)(r - 256) * 128 + jj];
    }
  } else if (bid < 769) {                // WgruCat row r: [x0|msg] -> [rsum|zsum|i_n|h_n]
    int r = bid - 513;
    for (int c = j; c < 512; c += 256) {
      float v;
      if (r < 128) v = (c < 384) ? W_ih[(size_t)r * 384 + c] : 0.f;
      else {
        int rm = r - 128;
        v = (c < 256) ? W_hh[(size_t)rm * 384 + c]
                      : (c < 384 ? 0.f : W_hh[(size_t)rm * 384 + 256 + (c - 384)]);
      }
      WgruCat[(size_t)r * 512 + c] = v;
    }
  } else if (bid == 769) {               // bgru
    bgru[j] = b_ih[j] + b_hh[j];                      // rsum/zsum biases (j<256)
    int c1 = j + 256;
    bgru[c1] = (c1 < 384) ? b_ih[c1] : b_hh[c1 - 128]; // i_n / h_n biases
  } else {                               // bid 770..869: zero cnt+cursor (2N ints)
    int g = ((bid - 770) * 256 + j) * 4;
    if (g < 2 * NN) *reinterpret_cast<int4*>(zint + g) = make_int4(0, 0, 0, 0);
  }
}

// ---------- K2: weight pack (blocks 0..39) + edge histogram (40..821) ----------
__global__ __launch_bounds__(1024) void pack_hist(
    const float* __restrict__ WcatQ, const float* __restrict__ WcatKV,
    const float* __restrict__ Wbig, const float* __restrict__ WgruCat,
    unsigned short* __restrict__ pQ, unsigned short* __restrict__ pKV,
    unsigned short* __restrict__ pBig, unsigned short* __restrict__ pGRU,
    const int* __restrict__ edges, int* __restrict__ cnt) {
  const int bid = blockIdx.x, tid = threadIdx.x;
  if (bid < 40) {
    int idx = bid * 1024 + tid;          // 0..40959
    const float* W; unsigned short* P; int KK, Nc;
    if (idx < 8192)       { W = WcatQ;   P = pQ;   KK = 128; Nc = 512; }
    else if (idx < 16384) { W = WcatKV;  P = pKV;  KK = 128; Nc = 512; idx -= 8192; }
    else if (idx < 24576) { W = Wbig;    P = pBig; KK = 512; Nc = 128; idx -= 16384; }
    else                  { W = WgruCat; P = pGRU; KK = 256; Nc = 512; idx -= 24576; }
    int nbs = Nc >> 4;
    int lane = idx & 63;
    int pair = idx >> 6;
    int kb = pair / nbs, nb = pair - kb * nbs;
    int kbase = kb * 32 + (lane >> 4) * 8;
    int col = nb * 16 + (lane & 15);
    unsigned short o[8];
#pragma unroll
    for (int j = 0; j < 8; ++j) o[j] = f2bf(W[(size_t)(kbase + j) * Nc + col]);
    *reinterpret_cast<bf16x8*>(P + (size_t)idx * 8) = *reinterpret_cast<bf16x8*>(o);
  } else {
    int e = (bid - 40) * 1024 + tid;
    if (e < EE) atomicAdd(&cnt[edges[EE + e]], 1);
  }
}

// ---------- K3: per-chunk inclusive scan (49 blocks x 1024, coalesced) ----------
__global__ __launch_bounds__(1024) void scan_partial(const int* __restrict__ cnt,
                                                     int* __restrict__ basep,
                                                     int* __restrict__ bsum) {
  __shared__ int sd[1024];
  int t = threadIdx.x, g = blockIdx.x * 1024 + t;
  int v = (g < NN) ? cnt[g] : 0;
  sd[t] = v;
  __syncthreads();
  for (int d = 1; d < 1024; d <<= 1) {
    int add = (t >= d) ? sd[t - d] : 0;
    __syncthreads();
    sd[t] += add;
    __syncthreads();
  }
  if (g < NN) basep[g] = sd[t] - v;
  if (t == 1023) bsum[blockIdx.x] = sd[1023];
}

// ---------- K4: finalize scan — per-block redundant bsum prefix + add ----------
__global__ __launch_bounds__(1024) void scan_final(const int* __restrict__ bsum,
                                                   const int* __restrict__ basep,
                                                   int* __restrict__ base) {
  __shared__ int s_off;
  const int bid = blockIdx.x, tid = threadIdx.x;
  if (tid < 64) {
    int v = (tid < 49) ? bsum[tid] : 0;
    int incl = v;
#pragma unroll
    for (int off = 1; off < 64; off <<= 1) {
      int o = __shfl_up(incl, off);
      if (tid >= off) incl += o;
    }
    int ex = (bid == 0) ? 0 : __shfl(incl, bid - 1);
    if (tid == 0) s_off = ex;
  }
  __syncthreads();
  int g = bid * 1024 + tid;
  if (g < NN) base[g] = basep[g] + s_off;
  if (bid == 48 && tid == 0) base[NN] = EE;
}

// ---------- MFMA bf16 GEMM body; OUT: 1=bf16, 2=f32+bf16; AF32: A is fp32 ----------
template <int OUT, int AF32, int NF, int EMITA>
__device__ __forceinline__ void gemm_body(
    int bx, int by, const void* __restrict__ Av, const unsigned short* __restrict__ Wp,
    const float* __restrict__ bias, float* __restrict__ C,
    unsigned short* __restrict__ Cbf, unsigned short* __restrict__ Abf,
    int M, int Arows, int K, int Nc) {
  const int wid = threadIdx.x >> 6, lane = threadIdx.x & 63;
  const int m0 = by * 64 + wid * 16;
  const int nb0 = bx * NF;
  const int nbs = Nc >> 4;
  const int row = m0 + (lane & 15);
  const int arow = min(row, Arows - 1);
  const int kq = lane >> 4;
  f32x4 acc[NF];
#pragma unroll
  for (int nf = 0; nf < NF; ++nf) acc[nf] = 0.f;
  const int nkb = K >> 5;
  for (int kb = 0; kb < nkb; ++kb) {
    bf16x8 a;
    if (AF32) {
      const float* ap = (const float*)Av + (size_t)arow * K + kb * 32 + kq * 8;
      const float4 f0 = *(const float4*)ap;
      const float4 f1 = *(const float4*)(ap + 4);
      unsigned short t[8] = {f2bf(f0.x), f2bf(f0.y), f2bf(f0.z), f2bf(f0.w),
                             f2bf(f1.x), f2bf(f1.y), f2bf(f1.z), f2bf(f1.w)};
      a = *reinterpret_cast<bf16x8*>(t);
      if (EMITA) {
        if (bx == 0)
          *reinterpret_cast<bf16x8*>(Abf + (size_t)arow * K + kb * 32 + kq * 8) = a;
      }
    } else {
      a = *reinterpret_cast<const bf16x8*>(
          (const unsigned short*)Av + (size_t)arow * K + kb * 32 + kq * 8);
    }
#pragma unroll
    for (int nf = 0; nf < NF; ++nf) {
      bf16x8 b = *reinterpret_cast<const bf16x8*>(
          Wp + ((size_t)(kb * nbs + nb0 + nf) * 64 + lane) * 8);
      acc[nf] = __builtin_amdgcn_mfma_f32_16x16x32_bf16(a, b, acc[nf], 0, 0, 0);
    }
  }
  const int crow0 = m0 + (lane >> 4) * 4;
  const int ccol = lane & 15;
#pragma unroll
  for (int nf = 0; nf < NF; ++nf) {
    const float bv = bias[(nb0 + nf) * 16 + ccol];
#pragma unroll
    for (int r = 0; r < 4; ++r) {
      float v = acc[nf][r] + bv;
      float vp = __shfl_xor(v, 1);
      const int rr = crow0 + r;
      if (rr < M) {
        if (OUT == 2)
          C[(size_t)rr * Nc + (nb0 + nf) * 16 + ccol] = v;
        if (!(lane & 1)) {
          ushort2 o;
          o.x = f2bf(v);
          o.y = f2bf(vp);
          *reinterpret_cast<ushort2*>(Cbf + (size_t)rr * Nc +
                                      (nb0 + nf) * 16 + (ccol & ~1)) = o;
        }
      }
    }
  }
}

template <int OUT, int AF32, int NF, int EMITA>
__global__ __launch_bounds__(256) void gemm_mfma(
    const void* __restrict__ Av, const unsigned short* __restrict__ Wp,
    const float* __restrict__ bias, float* __restrict__ C,
    unsigned short* __restrict__ Cbf, unsigned short* __restrict__ Abf,
    int M, int Arows, int K, int Nc) {
  gemm_body<OUT, AF32, NF, EMITA>(blockIdx.x, blockIdx.y, Av, Wp, bias, C, Cbf,
                                  Abf, M, Arows, K, Nc);
}

// ---------- K5: scatter (blocks 0..3124) + projQQ (..6252) + projKV (..9380) ----------
__global__ __launch_bounds__(256) void scatter_proj(
    const int* __restrict__ edges, const int* __restrict__ base,
    int* __restrict__ cursor, int2* __restrict__ epairs,
    const float* __restrict__ x0, const float* __restrict__ x1,
    const unsigned short* __restrict__ pQ, const unsigned short* __restrict__ pKV,
    const float* __restrict__ bcatQ, const float* __restrict__ bcatKV,
    unsigned short* __restrict__ QQbf, unsigned short* __restrict__ KVbf,
    unsigned short* __restrict__ x0bf) {
  const int bid = blockIdx.x;
  if (bid < 3125) {
    int e = bid * 256 + threadIdx.x;
    int s = edges[e];
    int d = edges[EE + e];
    int pos = base[d] + atomicAdd(&cursor[d], 1);
    epairs[pos] = make_int2(e, s);
  } else if (bid < 6253) {
    int pb = bid - 3125;
    gemm_body<1, 1, 8, 1>(pb & 3, pb >> 2, x0, pQ, bcatQ, nullptr, QQbf, x0bf,
                          NN, NN, 128, 512);
  } else {
    int pb = bid - 6253;
    gemm_body<1, 1, 8, 0>(pb & 3, pb >> 2, x1, pKV, bcatKV, nullptr, KVbf, nullptr,
                          NN, NN, 128, 512);
  }
}

// ---------- K6: fused attention: one wave per node, half-wave per edge ----------
// Linear row layout: 4x8B KV loads/lane-group = fully coalesced 256B half-wave
// requests (2 cache lines each) — measured optimal (r12 PERM regressed: per-lane
// contiguity breaks wave coalescing, 8 lines/request).
__global__ __launch_bounds__(256) void attn_wave_kernel(
    const float* __restrict__ edge_attr, const unsigned short* __restrict__ QQbf,
    const unsigned short* __restrict__ KVbf, const int* __restrict__ base,
    const int2* __restrict__ epairs, unsigned short* __restrict__ aggbf) {
  const int wid = threadIdx.x >> 6, lane = threadIdx.x & 63;
  const int n = blockIdx.x * 4 + wid;
  if (n >= NN) return;
  const int hh = lane >> 5;            // which edge of the pair
  const int l = lane & 31;             // elem group: 4 elems per 128-block
  const unsigned short* qp = QQbf + (size_t)n * 512 + 4 * l;
  const float4 q0 = bf2f4(*(const ushort4*)(qp));
  const float4 q1 = bf2f4(*(const ushort4*)(qp + 128));
  const float4 w0 = bf2f4(*(const ushort4*)(qp + 256));
  const float4 w1 = bf2f4(*(const ushort4*)(qp + 384));
  const int beg = base[n], end = base[n + 1];
  float s0 = 0.f, s1 = 0.f;
  float4 ae0 = {0.f, 0.f, 0.f, 0.f}, ae1 = {0.f, 0.f, 0.f, 0.f};
  float4 av0 = {0.f, 0.f, 0.f, 0.f}, av1 = {0.f, 0.f, 0.f, 0.f};
  const float SC = 0.08838834764831845f;
  for (int p = beg; p < end; p += 2) {
    const int pe = min(p + hh, end - 1);
    const bool act = (p + hh < end);
    const int2 es = epairs[pe];
    const fv4 eav = __builtin_nontemporal_load(
        (const fv4*)(edge_attr + (size_t)es.x * 128 + 4 * l));
    const float4 ea = {eav.x, eav.y, eav.z, eav.w};
    const unsigned short* kp = KVbf + (size_t)es.y * 512 + 4 * l;
    const float4 k0 = bf2f4(*(const ushort4*)(kp));
    const float4 k1 = bf2f4(*(const ushort4*)(kp + 128));
    const float4 v0 = bf2f4(*(const ushort4*)(kp + 256));
    const float4 v1 = bf2f4(*(const ushort4*)(kp + 384));
    float p0 = ea.x * w0.x + ea.y * w0.y + ea.z * w0.z + ea.w * w0.w
             + q0.x * k0.x + q0.y * k0.y + q0.z * k0.z + q0.w * k0.w;
    float p1 = ea.x * w1.x + ea.y * w1.y + ea.z * w1.z + ea.w * w1.w
             + q1.x * k1.x + q1.y * k1.y + q1.z * k1.z + q1.w * k1.w;
#pragma unroll
    for (int off = 16; off; off >>= 1) {
      p0 += __shfl_xor(p0, off);
      p1 += __shfl_xor(p1, off);
    }
    float a0 = p0 * SC; a0 = (a0 < 0.f) ? 0.2f * a0 : a0;
    float a1 = p1 * SC; a1 = (a1 < 0.f) ? 0.2f * a1 : a1;
    const float x0 = act ? __expf(a0) : 0.f;
    const float x1 = act ? __expf(a1) : 0.f;
    s0 += x0; s1 += x1;
    ae0.x += x0 * ea.x; ae0.y += x0 * ea.y; ae0.z += x0 * ea.z; ae0.w += x0 * ea.w;
    ae1.x += x1 * ea.x; ae1.y += x1 * ea.y; ae1.z += x1 * ea.z; ae1.w += x1 * ea.w;
    av0.x += x0 * v0.x; av0.y += x0 * v0.y; av0.z += x0 * v0.z; av0.w += x0 * v0.w;
    av1.x += x1 * v1.x; av1.y += x1 * v1.y; av1.z += x1 * v1.z; av1.w += x1 * v1.w;
  }
  // combine the two half-wave accumulators
  s0 += __shfl_xor(s0, 32); s1 += __shfl_xor(s1, 32);
  ae0.x += __shfl_xor(ae0.x, 32); ae0.y += __shfl_xor(ae0.y, 32);
  ae0.z += __shfl_xor(ae0.z, 32); ae0.w += __shfl_xor(ae0.w, 32);
  ae1.x += __shfl_xor(ae1.x, 32); ae1.y += __shfl_xor(ae1.y, 32);
  ae1.z += __shfl_xor(ae1.z, 32); ae1.w += __shfl_xor(ae1.w, 32);
  av0.x += __shfl_xor(av0.x, 32); av0.y += __shfl_xor(av0.y, 32);
  av0.z += __shfl_xor(av0.z, 32); av0.w += __shfl_xor(av0.w, 32);
  av1.x += __shfl_xor(av1.x, 32); av1.y += __shfl_xor(av1.y, 32);
  av1.z += __shfl_xor(av1.z, 32); av1.w += __shfl_xor(av1.w, 32);
  const float i0 = 1.f / (s0 + 1e-16f), i1 = 1.f / (s1 + 1e-16f);
  if (hh == 0) {
    unsigned short* op = aggbf + (size_t)n * 512 + 4 * l;
    ushort4 o;
    o.x = f2bf(ae0.x * i0); o.y = f2bf(ae0.y * i0);
    o.z = f2bf(ae0.z * i0); o.w = f2bf(ae0.w * i0);
    *(ushort4*)op = o;
    o.x = f2bf(ae1.x * i1); o.y = f2bf(ae1.y * i1);
    o.z = f2bf(ae1.z * i1); o.w = f2bf(ae1.w * i1);
    *(ushort4*)(op + 128) = o;
    o.x = f2bf(av0.x * i0); o.y = f2bf(av0.y * i0);
    o.z = f2bf(av0.z * i0); o.w = f2bf(av0.w * i0);
    *(ushort4*)(op + 256) = o;
    o.x = f2bf(av1.x * i1); o.y = f2bf(av1.y * i1);
    o.z = f2bf(av1.z * i1); o.w = f2bf(av1.w * i1);
    *(ushort4*)(op + 384) = o;
  }
}

// ---------- K8: fused GRU: [x0|msg] @ WgruCat -> gates -> out ----------
__global__ __launch_bounds__(256) void gru_fused(
    const unsigned short* __restrict__ x0bf, const unsigned short* __restrict__ msgbf,
    const unsigned short* __restrict__ pGRU, const float* __restrict__ bgru,
    float* __restrict__ out) {
  const int wid = threadIdx.x >> 6, lane = threadIdx.x & 63;
  const int m0 = blockIdx.y * 64 + wid * 16;
  const int xq = blockIdx.x;           // output-dim quarter: d in [xq*32, xq*32+32)
  const int row = m0 + (lane & 15);
  const int ar = min(row, NN - 1);
  const int kq = lane >> 4;
  f32x4 acc[4][2];
#pragma unroll
  for (int g = 0; g < 4; ++g)
#pragma unroll
    for (int f = 0; f < 2; ++f) acc[g][f] = 0.f;
  for (int kb = 0; kb < 8; ++kb) {
    bf16x8 a;
    if (kb < 4) {
      a = *reinterpret_cast<const bf16x8*>(x0bf + (size_t)ar * 128 +
                                           kb * 32 + kq * 8);
    } else {
      a = *reinterpret_cast<const bf16x8*>(msgbf + (size_t)ar * 128 +
                                           (kb - 4) * 32 + kq * 8);
    }
#pragma unroll
    for (int g = 0; g < 4; ++g)
#pragma unroll
      for (int f = 0; f < 2; ++f) {
        const int nf = g * 8 + xq * 2 + f;
        bf16x8 b = *reinterpret_cast<const bf16x8*>(
            pGRU + ((size_t)(kb * 32 + nf) * 64 + lane) * 8);
        acc[g][f] = __builtin_amdgcn_mfma_f32_16x16x32_bf16(a, b, acc[g][f], 0, 0, 0);
      }
  }
  const int crow0 = m0 + (lane >> 4) * 4;
  const int ccol = lane & 15;
#pragma unroll
  for (int f = 0; f < 2; ++f) {
    const int d = xq * 32 + f * 16 + ccol;
    const float brs = bgru[d], bzs = bgru[128 + d];
    const float bin = bgru[256 + d], bhn = bgru[384 + d];
#pragma unroll
    for (int r = 0; r < 4; ++r) {
      const int rr = crow0 + r;
      if (rr < NN) {
        const float rs = acc[0][f][r] + brs;
        const float zs = acc[1][f][r] + bzs;
        const float iv = acc[2][f][r] + bin;
        const float hv = acc[3][f][r] + bhn;
        const float rg = 1.f / (1.f + __expf(-rs));
        const float zg = 1.f / (1.f + __expf(-zs));
        const float ng = tanhf(iv + rg * hv);
        const float h = bf2f(msgbf[(size_t)rr * 128 + d]);
        out[(size_t)rr * 128 + d] = (1.f - zg) * ng + zg * h;
      }
    }
  }
}

extern "C" void kernel_launch(void* const* d_in, const int* in_sizes, int n_in,
                              void* d_out, int out_size, void* d_ws, size_t ws_size,
                              hipStream_t stream) {
  const float* x0 = (const float*)d_in[0];
  const float* x1 = (const float*)d_in[1];
  const float* edge_attr = (const float*)d_in[2];
  const int* edges = (const int*)d_in[3];
  const float* Wq = (const float*)d_in[5];
  const float* bq = (const float*)d_in[6];
  const float* Wk = (const float*)d_in[7];
  const float* bk = (const float*)d_in[8];
  const float* Wv = (const float*)d_in[9];
  const float* bv = (const float*)d_in[10];
  const float* Wo = (const float*)d_in[11];
  const float* bo = (const float*)d_in[12];
  const float* W_ih = (const float*)d_in[13];
  const float* b_ih = (const float*)d_in[14];
  const float* W_hh = (const float*)d_in[15];
  const float* b_hh = (const float*)d_in[16];
  float* out = (float*)d_out;
  float* wsf = (float*)d_ws;

  unsigned short* QQbf  = (unsigned short*)(wsf + OFF_QQBF);
  unsigned short* KVbf  = (unsigned short*)(wsf + OFF_KVBF);
  unsigned short* aggbf = (unsigned short*)(wsf + OFF_AGGBF);
  unsigned short* msgbf = (unsigned short*)(wsf + OFF_MSGBF);
  unsigned short* x0bf  = (unsigned short*)(wsf + OFF_X0BF);
  int* ip    = (int*)(wsf + OFF_INT);
  int* cntb  = ip;                       // N
  int* curb  = ip + NN;                  // N
  int* bpart = ip + 2 * NN;              // N
  int* baseb = ip + 3 * NN;              // N+1
  int* bsumb = ip + 4 * NN + 1;          // 64
  int2* epairs = (int2*)(ip + 4 * NN + 130);   // 2E ints, 8B aligned
  float* WcatQ  = wsf + OFF_WCATQ;
  float* WcatKV = wsf + OFF_WCATKV;
  float* Wbigb  = wsf + OFF_WBIG;
  float* WgruC  = wsf + OFF_WGRU;
  float* bcatQ  = wsf + OFF_BCATQ;
  float* bcatKV = wsf + OFF_BCATKV;
  float* bgru   = wsf + OFF_BGRU;
  unsigned short* pQ   = (unsigned short*)(wsf + OFF_PQ);
  unsigned short* pKV  = (unsigned short*)(wsf + OFF_PKV);
  unsigned short* pBig = (unsigned short*)(wsf + OFF_PBIG);
  unsigned short* pGRU = (unsigned short*)(wsf + OFF_PGRU);

  // K1: weight prep + zero sort counters
  prep_all<<<870, 256, 0, stream>>>(Wq, bq, Wk, bk, Wv, bv, Wo, W_ih, b_ih,
                                    W_hh, b_hh, WcatQ, bcatQ, WcatKV, bcatKV,
                                    Wbigb, WgruC, bgru, ip);
  // K2: pack weights + histogram
  pack_hist<<<822, 1024, 0, stream>>>(WcatQ, WcatKV, Wbigb, WgruC,
                                      pQ, pKV, pBig, pGRU, edges, cntb);
  // K3/K4: two-level coalesced scan
  scan_partial<<<49, 1024, 0, stream>>>(cntb, bpart, bsumb);
  scan_final<<<49, 1024, 0, stream>>>(bsumb, bpart, baseb);
  // K5: scatter + both projection GEMMs
  scatter_proj<<<9381, 256, 0, stream>>>(edges, baseb, curb, epairs,
                                         x0, x1, pQ, pKV, bcatQ, bcatKV,
                                         QQbf, KVbf, x0bf);
  // K6: fused attention
  attn_wave_kernel<<<(NN + 3) / 4, 256, 0, stream>>>(edge_attr, QQbf, KVbf,
                                                     baseb, epairs, aggbf);
  // K7: msg = aggbf @ pBig + bo (bf16 out only)
  gemm_mfma<1, 0, 4, 0><<<dim3(2, MPAD / 64), 256, 0, stream>>>(
      aggbf, pBig, bo, nullptr, msgbf, nullptr, NN, NN, 512, 128);
  // K8: fused GRU -> out
  gru_fused<<<dim3(4, MPAD / 64), 256, 0, stream>>>(x0bf, msgbf, pGRU, bgru, out);
}

// Round 14
// 397.424 us; speedup vs baseline: 1.2063x; 1.1106x over previous
//
#include <hip/hip_runtime.h>
#include <hip/hip_bf16.h>
#include <math.h>

#define NN 50000
#define EE 800000
#define MPAD 50048          // 64-aligned row pad for MFMA GEMMs

// ---------- workspace layout (offsets in floats) ----------
#define OFF_QQBF   0ull          // MPAD*512 bf16 = 12,812,288 fl
#define OFF_KVBF   12900000ull   // MPAD*384 bf16 = 9,609,216 fl  [K1(256) | x1bf(128)]
#define OFF_AGGBF  25900000ull   // MPAD*512 bf16
#define OFF_MSGBF  45300000ull   // MPAD*128 bf16 = 3,203,072 fl
#define OFF_INT    48600000ull   // ints: 4N+130+2E = 1,800,130
#define OFF_WCATQ  50500000ull   // 128*512 fp32
#define OFF_WCATKV 50600000ull   // 128*256 fp32 (Wk2 only)
#define OFF_WBIG   50700000ull   // 512*128 fp32 (Wv1Wo | Wv2Wo per head)
#define OFF_WGRU   50800000ull   // 256*512 fp32
#define OFF_BCATQ  51000000ull   // 512
#define OFF_BCATKV 51001000ull   // 256
#define OFF_BGRU   51002000ull   // 512
#define OFF_BO2    51003000ull   // 128 (bo + bv@Wo)
#define OFF_PQ     51010000ull   // packed bf16
#define OFF_PKV    51050000ull
#define OFF_PBIG   51090000ull
#define OFF_PGRU   51130000ull   // 131072 shorts
#define OFF_X0BF   51200000ull   // MPAD*128 bf16 = 3,203,072 fl
// end ~54.41M floats = 218 MB

typedef short bf16x8 __attribute__((ext_vector_type(8)));
typedef float f32x4 __attribute__((ext_vector_type(4)));
typedef float fv4 __attribute__((ext_vector_type(4)));    // native vec for nontemporal

__device__ inline unsigned short f2bf(float f) {   // round-to-nearest-even
  unsigned u = __float_as_uint(f);
  return (unsigned short)((u + 0x7FFFu + ((u >> 16) & 1u)) >> 16);
}
__device__ inline float bf2f(unsigned short u) {
  return __uint_as_float((unsigned)u << 16);
}
__device__ inline float4 bf2f4(ushort4 u) {
  float4 r;
  r.x = bf2f(u.x); r.y = bf2f(u.y); r.z = bf2f(u.z); r.w = bf2f(u.w);
  return r;
}

// ---------- K1: weight prep + sort-counter zeroing: 871 blocks x 256 ----------
__global__ void prep_all(const float* __restrict__ Wq, const float* __restrict__ bq,
                         const float* __restrict__ Wk, const float* __restrict__ bk,
                         const float* __restrict__ Wv, const float* __restrict__ bv,
                         const float* __restrict__ Wo, const float* __restrict__ bo,
                         const float* __restrict__ W_ih, const float* __restrict__ b_ih,
                         const float* __restrict__ W_hh, const float* __restrict__ b_hh,
                         float* __restrict__ WcatQ, float* __restrict__ bcatQ,
                         float* __restrict__ WcatKV, float* __restrict__ bcatKV,
                         float* __restrict__ Wbig, float* __restrict__ WgruCat,
                         float* __restrict__ bgru, float* __restrict__ bo2,
                         int* __restrict__ zint) {
  const int bid = blockIdx.x, j = threadIdx.x;
  if (bid < 129) {                       // Wqk = Wq @ Wk_h^T per head (+ bias row)
    int c0 = bid, h = j >> 7, c = j & 127;
    const float* wkrow = Wk + (size_t)c * 256 + h * 128;
    float acc = 0.f;
    if (c0 < 128) {
      const float* wqrow = Wq + (size_t)c0 * 256 + h * 128;
      for (int d = 0; d < 128; d++) acc += wqrow[d] * wkrow[d];
      WcatQ[c0 * 512 + 256 + j] = acc;
    } else {
      for (int d = 0; d < 128; d++) acc += bq[h * 128 + d] * wkrow[d];
      bcatQ[256 + j] = acc;
    }
  } else if (bid < 257) {                // pack Wq / Wk2 + biases
    int r = bid - 129;
    WcatQ[r * 512 + j] = Wq[r * 256 + j];
    if (j < 256) WcatKV[r * 256 + j] = Wk[(size_t)(128 + r) * 256 + j];
    if (r == 0) {
      bcatQ[j] = bq[j];
      if (j < 256) bcatKV[j] = bk[j];
    }
  } else if (bid < 513) {                // Wbig (2 rows per block): Wv1Wo | Wv2Wo
    int r = (bid - 257) * 2 + (j >> 7), jj = j & 127;
    int h = (r >> 7) & 1, c = r & 127;
    int srow = (r < 256) ? c : 128 + c;  // Wv1 rows 0..127, Wv2 rows 128..255
    float acc = 0.f;
    for (int d = 0; d < 128; d++)
      acc += Wv[(size_t)srow * 256 + h * 128 + d] * Wo[(size_t)(h * 128 + d) * 128 + jj];
    Wbig[r * 128 + jj] = acc;
  } else if (bid < 769) {                // WgruCat row r: [x0|msg] -> [rsum|zsum|i_n|h_n]
    int r = bid - 513;
    for (int c = j; c < 512; c += 256) {
      float v;
      if (r < 128) v = (c < 384) ? W_ih[(size_t)r * 384 + c] : 0.f;
      else {
        int rm = r - 128;
        v = (c < 256) ? W_hh[(size_t)rm * 384 + c]
                      : (c < 384 ? 0.f : W_hh[(size_t)rm * 384 + 256 + (c - 384)]);
      }
      WgruCat[(size_t)r * 512 + c] = v;
    }
  } else if (bid == 769) {               // bgru
    bgru[j] = b_ih[j] + b_hh[j];                      // rsum/zsum biases (j<256)
    int c1 = j + 256;
    bgru[c1] = (c1 < 384) ? b_ih[c1] : b_hh[c1 - 128]; // i_n / h_n biases
  } else if (bid == 770) {               // bo2 = bo + bv@Wo
    if (j < 128) {
      float acc = bo[j];
      for (int t = 0; t < 256; t++) acc += bv[t] * Wo[(size_t)t * 128 + j];
      bo2[j] = acc;
    }
  } else {                               // bid 771..870: zero cnt+cursor (2N ints)
    int g = ((bid - 771) * 256 + j) * 4;
    if (g < 2 * NN) *reinterpret_cast<int4*>(zint + g) = make_int4(0, 0, 0, 0);
  }
}

// ---------- K2: weight pack (blocks 0..35) + edge histogram (36..817) ----------
__global__ __launch_bounds__(1024) void pack_hist(
    const float* __restrict__ WcatQ, const float* __restrict__ WcatKV,
    const float* __restrict__ Wbig, const float* __restrict__ WgruCat,
    unsigned short* __restrict__ pQ, unsigned short* __restrict__ pKV,
    unsigned short* __restrict__ pBig, unsigned short* __restrict__ pGRU,
    const int* __restrict__ edges, int* __restrict__ cnt) {
  const int bid = blockIdx.x, tid = threadIdx.x;
  if (bid < 36) {
    int idx = bid * 1024 + tid;          // 0..36863
    const float* W; unsigned short* P; int Nc;
    if (idx < 8192)       { W = WcatQ;   P = pQ;   Nc = 512; }
    else if (idx < 12288) { W = WcatKV;  P = pKV;  Nc = 256; idx -= 8192; }
    else if (idx < 20480) { W = Wbig;    P = pBig; Nc = 128; idx -= 12288; }
    else                  { W = WgruCat; P = pGRU; Nc = 512; idx -= 20480; }
    int nbs = Nc >> 4;
    int lane = idx & 63;
    int pair = idx >> 6;
    int kb = pair / nbs, nb = pair - kb * nbs;
    int kbase = kb * 32 + (lane >> 4) * 8;
    int col = nb * 16 + (lane & 15);
    unsigned short o[8];
#pragma unroll
    for (int j = 0; j < 8; ++j) o[j] = f2bf(W[(size_t)(kbase + j) * Nc + col]);
    *reinterpret_cast<bf16x8*>(P + (size_t)idx * 8) = *reinterpret_cast<bf16x8*>(o);
  } else {
    int e = (bid - 36) * 1024 + tid;
    if (e < EE) atomicAdd(&cnt[edges[EE + e]], 1);
  }
}

// ---------- K3: per-chunk inclusive scan (49 blocks x 1024, coalesced) ----------
__global__ __launch_bounds__(1024) void scan_partial(const int* __restrict__ cnt,
                                                     int* __restrict__ basep,
                                                     int* __restrict__ bsum) {
  __shared__ int sd[1024];
  int t = threadIdx.x, g = blockIdx.x * 1024 + t;
  int v = (g < NN) ? cnt[g] : 0;
  sd[t] = v;
  __syncthreads();
  for (int d = 1; d < 1024; d <<= 1) {
    int add = (t >= d) ? sd[t - d] : 0;
    __syncthreads();
    sd[t] += add;
    __syncthreads();
  }
  if (g < NN) basep[g] = sd[t] - v;
  if (t == 1023) bsum[blockIdx.x] = sd[1023];
}

// ---------- K4: finalize scan — per-block redundant bsum prefix + add ----------
__global__ __launch_bounds__(1024) void scan_final(const int* __restrict__ bsum,
                                                   const int* __restrict__ basep,
                                                   int* __restrict__ base) {
  __shared__ int s_off;
  const int bid = blockIdx.x, tid = threadIdx.x;
  if (tid < 64) {
    int v = (tid < 49) ? bsum[tid] : 0;
    int incl = v;
#pragma unroll
    for (int off = 1; off < 64; off <<= 1) {
      int o = __shfl_up(incl, off);
      if (tid >= off) incl += o;
    }
    int ex = (bid == 0) ? 0 : __shfl(incl, bid - 1);
    if (tid == 0) s_off = ex;
  }
  __syncthreads();
  int g = bid * 1024 + tid;
  if (g < NN) base[g] = basep[g] + s_off;
  if (bid == 48 && tid == 0) base[NN] = EE;
}

// ---------- MFMA bf16 GEMM body ----------
// OUT: 1=bf16, 2=f32+bf16; AF32: A is fp32.
// EMITA: 0=none; 1=store A-frags linear (stride K) to Abf when bx==0;
//        2=store A-frags to Abf row stride 384, col offset 256 (KVbf x1 slot).
// ldc = C/Cbf row stride (elements).
template <int OUT, int AF32, int NF, int EMITA>
__device__ __forceinline__ void gemm_body(
    int bx, int by, const void* __restrict__ Av, const unsigned short* __restrict__ Wp,
    const float* __restrict__ bias, float* __restrict__ C,
    unsigned short* __restrict__ Cbf, unsigned short* __restrict__ Abf,
    int M, int Arows, int K, int Nc, int ldc) {
  const int wid = threadIdx.x >> 6, lane = threadIdx.x & 63;
  const int m0 = by * 64 + wid * 16;
  const int nb0 = bx * NF;
  const int nbs = Nc >> 4;
  const int row = m0 + (lane & 15);
  const int arow = min(row, Arows - 1);
  const int kq = lane >> 4;
  f32x4 acc[NF];
#pragma unroll
  for (int nf = 0; nf < NF; ++nf) acc[nf] = 0.f;
  const int nkb = K >> 5;
  for (int kb = 0; kb < nkb; ++kb) {
    bf16x8 a;
    if (AF32) {
      const float* ap = (const float*)Av + (size_t)arow * K + kb * 32 + kq * 8;
      const float4 f0 = *(const float4*)ap;
      const float4 f1 = *(const float4*)(ap + 4);
      unsigned short t[8] = {f2bf(f0.x), f2bf(f0.y), f2bf(f0.z), f2bf(f0.w),
                             f2bf(f1.x), f2bf(f1.y), f2bf(f1.z), f2bf(f1.w)};
      a = *reinterpret_cast<bf16x8*>(t);
      if (EMITA == 1) {
        if (bx == 0)
          *reinterpret_cast<bf16x8*>(Abf + (size_t)arow * K + kb * 32 + kq * 8) = a;
      } else if (EMITA == 2) {
        if (bx == 0)
          *reinterpret_cast<bf16x8*>(Abf + (size_t)arow * 384 + 256 +
                                     kb * 32 + kq * 8) = a;
      }
    } else {
      a = *reinterpret_cast<const bf16x8*>(
          (const unsigned short*)Av + (size_t)arow * K + kb * 32 + kq * 8);
    }
#pragma unroll
    for (int nf = 0; nf < NF; ++nf) {
      bf16x8 b = *reinterpret_cast<const bf16x8*>(
          Wp + ((size_t)(kb * nbs + nb0 + nf) * 64 + lane) * 8);
      acc[nf] = __builtin_amdgcn_mfma_f32_16x16x32_bf16(a, b, acc[nf], 0, 0, 0);
    }
  }
  const int crow0 = m0 + (lane >> 4) * 4;
  const int ccol = lane & 15;
#pragma unroll
  for (int nf = 0; nf < NF; ++nf) {
    const float bv = bias[(nb0 + nf) * 16 + ccol];
#pragma unroll
    for (int r = 0; r < 4; ++r) {
      float v = acc[nf][r] + bv;
      float vp = __shfl_xor(v, 1);
      const int rr = crow0 + r;
      if (rr < M) {
        if (OUT == 2)
          C[(size_t)rr * ldc + (nb0 + nf) * 16 + ccol] = v;
        if (!(lane & 1)) {
          ushort2 o;
          o.x = f2bf(v);
          o.y = f2bf(vp);
          *reinterpret_cast<ushort2*>(Cbf + (size_t)rr * ldc +
                                      (nb0 + nf) * 16 + (ccol & ~1)) = o;
        }
      }
    }
  }
}

template <int OUT, int AF32, int NF, int EMITA>
__global__ __launch_bounds__(256) void gemm_mfma(
    const void* __restrict__ Av, const unsigned short* __restrict__ Wp,
    const float* __restrict__ bias, float* __restrict__ C,
    unsigned short* __restrict__ Cbf, unsigned short* __restrict__ Abf,
    int M, int Arows, int K, int Nc, int ldc) {
  gemm_body<OUT, AF32, NF, EMITA>(blockIdx.x, blockIdx.y, Av, Wp, bias, C, Cbf,
                                  Abf, M, Arows, K, Nc, ldc);
}

// ---------- K5: scatter (0..3124) + projQQ (3125..6252) + projK1 (6253..7816) ----------
__global__ __launch_bounds__(256) void scatter_proj(
    const int* __restrict__ edges, const int* __restrict__ base,
    int* __restrict__ cursor, int2* __restrict__ epairs,
    const float* __restrict__ x0, const float* __restrict__ x1,
    const unsigned short* __restrict__ pQ, const unsigned short* __restrict__ pKV,
    const float* __restrict__ bcatQ, const float* __restrict__ bcatKV,
    unsigned short* __restrict__ QQbf, unsigned short* __restrict__ KVbf,
    unsigned short* __restrict__ x0bf) {
  const int bid = blockIdx.x;
  if (bid < 3125) {
    int e = bid * 256 + threadIdx.x;
    int s = edges[e];
    int d = edges[EE + e];
    int pos = base[d] + atomicAdd(&cursor[d], 1);
    epairs[pos] = make_int2(e, s);
  } else if (bid < 6253) {
    int pb = bid - 3125;
    gemm_body<1, 1, 8, 1>(pb & 3, pb >> 2, x0, pQ, bcatQ, nullptr, QQbf, x0bf,
                          NN, NN, 128, 512, 512);
  } else {
    int pb = bid - 6253;   // K1 projection: Nc=256, ldc=384, emits x1bf cols 256+
    gemm_body<1, 1, 8, 2>(pb & 1, pb >> 1, x1, pKV, bcatKV, nullptr, KVbf, KVbf,
                          NN, NN, 128, 256, 384);
  }
}

// ---------- K6: fused attention: one wave per node, half-wave per edge ----------
// KVbf row = [K1 (256 bf16) | x1bf (128 bf16)], 768B. Per edge: 3x8B KV loads
// (was 4) — x1 gathered once, multiplied by both heads' weights; V = x1@Wv2
// folded into Wbig rows 256..511.
__global__ __launch_bounds__(256) void attn_wave_kernel(
    const float* __restrict__ edge_attr, const unsigned short* __restrict__ QQbf,
    const unsigned short* __restrict__ KVbf, const int* __restrict__ base,
    const int2* __restrict__ epairs, unsigned short* __restrict__ aggbf) {
  const int wid = threadIdx.x >> 6, lane = threadIdx.x & 63;
  const int n = blockIdx.x * 4 + wid;
  if (n >= NN) return;
  const int hh = lane >> 5;            // which edge of the pair
  const int l = lane & 31;             // elem group: 4 elems per 128-block
  const unsigned short* qp = QQbf + (size_t)n * 512 + 4 * l;
  const float4 q0 = bf2f4(*(const ushort4*)(qp));
  const float4 q1 = bf2f4(*(const ushort4*)(qp + 128));
  const float4 w0 = bf2f4(*(const ushort4*)(qp + 256));
  const float4 w1 = bf2f4(*(const ushort4*)(qp + 384));
  const int beg = base[n], end = base[n + 1];
  float s0 = 0.f, s1 = 0.f;
  float4 ae0 = {0.f, 0.f, 0.f, 0.f}, ae1 = {0.f, 0.f, 0.f, 0.f};
  float4 av0 = {0.f, 0.f, 0.f, 0.f}, av1 = {0.f, 0.f, 0.f, 0.f};
  const float SC = 0.08838834764831845f;
  for (int p = beg; p < end; p += 2) {
    const int pe = min(p + hh, end - 1);
    const bool act = (p + hh < end);
    const int2 es = epairs[pe];
    const fv4 eav = __builtin_nontemporal_load(
        (const fv4*)(edge_attr + (size_t)es.x * 128 + 4 * l));
    const float4 ea = {eav.x, eav.y, eav.z, eav.w};
    const unsigned short* kp = KVbf + (size_t)es.y * 384 + 4 * l;
    const float4 k0 = bf2f4(*(const ushort4*)(kp));
    const float4 k1 = bf2f4(*(const ushort4*)(kp + 128));
    const float4 xb = bf2f4(*(const ushort4*)(kp + 256));
    float p0 = ea.x * w0.x + ea.y * w0.y + ea.z * w0.z + ea.w * w0.w
             + q0.x * k0.x + q0.y * k0.y + q0.z * k0.z + q0.w * k0.w;
    float p1 = ea.x * w1.x + ea.y * w1.y + ea.z * w1.z + ea.w * w1.w
             + q1.x * k1.x + q1.y * k1.y + q1.z * k1.z + q1.w * k1.w;
#pragma unroll
    for (int off = 16; off; off >>= 1) {
      p0 += __shfl_xor(p0, off);
      p1 += __shfl_xor(p1, off);
    }
    float a0 = p0 * SC; a0 = (a0 < 0.f) ? 0.2f * a0 : a0;
    float a1 = p1 * SC; a1 = (a1 < 0.f) ? 0.2f * a1 : a1;
    const float x0 = act ? __expf(a0) : 0.f;
    const float x1 = act ? __expf(a1) : 0.f;
    s0 += x0; s1 += x1;
    ae0.x += x0 * ea.x; ae0.y += x0 * ea.y; ae0.z += x0 * ea.z; ae0.w += x0 * ea.w;
    ae1.x += x1 * ea.x; ae1.y += x1 * ea.y; ae1.z += x1 * ea.z; ae1.w += x1 * ea.w;
    av0.x += x0 * xb.x; av0.y += x0 * xb.y; av0.z += x0 * xb.z; av0.w += x0 * xb.w;
    av1.x += x1 * xb.x; av1.y += x1 * xb.y; av1.z += x1 * xb.z; av1.w += x1 * xb.w;
  }
  // combine the two half-wave accumulators
  s0 += __shfl_xor(s0, 32); s1 += __shfl_xor(s1, 32);
  ae0.x += __shfl_xor(ae0.x, 32); ae0.y += __shfl_xor(ae0.y, 32);
  ae0.z += __shfl_xor(ae0.z, 32); ae0.w += __shfl_xor(ae0.w, 32);
  ae1.x += __shfl_xor(ae1.x, 32); ae1.y += __shfl_xor(ae1.y, 32);
  ae1.z += __shfl_xor(ae1.z, 32); ae1.w += __shfl_xor(ae1.w, 32);
  av0.x += __shfl_xor(av0.x, 32); av0.y += __shfl_xor(av0.y, 32);
  av0.z += __shfl_xor(av0.z, 32); av0.w += __shfl_xor(av0.w, 32);
  av1.x += __shfl_xor(av1.x, 32); av1.y += __shfl_xor(av1.y, 32);
  av1.z += __shfl_xor(av1.z, 32); av1.w += __shfl_xor(av1.w, 32);
  const float i0 = 1.f / (s0 + 1e-16f), i1 = 1.f / (s1 + 1e-16f);
  if (hh == 0) {
    unsigned short* op = aggbf + (size_t)n * 512 + 4 * l;
    ushort4 o;
    o.x = f2bf(ae0.x * i0); o.y = f2bf(ae0.y * i0);
    o.z = f2bf(ae0.z * i0); o.w = f2bf(ae0.w * i0);
    *(ushort4*)op = o;
    o.x = f2bf(ae1.x * i1); o.y = f2bf(ae1.y * i1);
    o.z = f2bf(ae1.z * i1); o.w = f2bf(ae1.w * i1);
    *(ushort4*)(op + 128) = o;
    o.x = f2bf(av0.x * i0); o.y = f2bf(av0.y * i0);
    o.z = f2bf(av0.z * i0); o.w = f2bf(av0.w * i0);
    *(ushort4*)(op + 256) = o;
    o.x = f2bf(av1.x * i1); o.y = f2bf(av1.y * i1);
    o.z = f2bf(av1.z * i1); o.w = f2bf(av1.w * i1);
    *(ushort4*)(op + 384) = o;
  }
}

// ---------- K8: fused GRU: [x0|msg] @ WgruCat -> gates -> out ----------
__global__ __launch_bounds__(256) void gru_fused(
    const unsigned short* __restrict__ x0bf, const unsigned short* __restrict__ msgbf,
    const unsigned short* __restrict__ pGRU, const float* __restrict__ bgru,
    float* __restrict__ out) {
  const int wid = threadIdx.x >> 6, lane = threadIdx.x & 63;
  const int m0 = blockIdx.y * 64 + wid * 16;
  const int xq = blockIdx.x;           // output-dim quarter: d in [xq*32, xq*32+32)
  const int row = m0 + (lane & 15);
  const int ar = min(row, NN - 1);
  const int kq = lane >> 4;
  f32x4 acc[4][2];
#pragma unroll
  for (int g = 0; g < 4; ++g)
#pragma unroll
    for (int f = 0; f < 2; ++f) acc[g][f] = 0.f;
  for (int kb = 0; kb < 8; ++kb) {
    bf16x8 a;
    if (kb < 4) {
      a = *reinterpret_cast<const bf16x8*>(x0bf + (size_t)ar * 128 +
                                           kb * 32 + kq * 8);
    } else {
      a = *reinterpret_cast<const bf16x8*>(msgbf + (size_t)ar * 128 +
                                           (kb - 4) * 32 + kq * 8);
    }
#pragma unroll
    for (int g = 0; g < 4; ++g)
#pragma unroll
      for (int f = 0; f < 2; ++f) {
        const int nf = g * 8 + xq * 2 + f;
        bf16x8 b = *reinterpret_cast<const bf16x8*>(
            pGRU + ((size_t)(kb * 32 + nf) * 64 + lane) * 8);
        acc[g][f] = __builtin_amdgcn_mfma_f32_16x16x32_bf16(a, b, acc[g][f], 0, 0, 0);
      }
  }
  const int crow0 = m0 + (lane >> 4) * 4;
  const int ccol = lane & 15;
#pragma unroll
  for (int f = 0; f < 2; ++f) {
    const int d = xq * 32 + f * 16 + ccol;
    const float brs = bgru[d], bzs = bgru[128 + d];
    const float bin = bgru[256 + d], bhn = bgru[384 + d];
#pragma unroll
    for (int r = 0; r < 4; ++r) {
      const int rr = crow0 + r;
      if (rr < NN) {
        const float rs = acc[0][f][r] + brs;
        const float zs = acc[1][f][r] + bzs;
        const float iv = acc[2][f][r] + bin;
        const float hv = acc[3][f][r] + bhn;
        const float rg = 1.f / (1.f + __expf(-rs));
        const float zg = 1.f / (1.f + __expf(-zs));
        const float ng = tanhf(iv + rg * hv);
        const float h = bf2f(msgbf[(size_t)rr * 128 + d]);
        out[(size_t)rr * 128 + d] = (1.f - zg) * ng + zg * h;
      }
    }
  }
}

extern "C" void kernel_launch(void* const* d_in, const int* in_sizes, int n_in,
                              void* d_out, int out_size, void* d_ws, size_t ws_size,
                              hipStream_t stream) {
  const float* x0 = (const float*)d_in[0];
  const float* x1 = (const float*)d_in[1];
  const float* edge_attr = (const float*)d_in[2];
  const int* edges = (const int*)d_in[3];
  const float* Wq = (const float*)d_in[5];
  const float* bq = (const float*)d_in[6];
  const float* Wk = (const float*)d_in[7];
  const float* bk = (const float*)d_in[8];
  const float* Wv = (const float*)d_in[9];
  const float* bv = (const float*)d_in[10];
  const float* Wo = (const float*)d_in[11];
  const float* bo = (const float*)d_in[12];
  const float* W_ih = (const float*)d_in[13];
  const float* b_ih = (const float*)d_in[14];
  const float* W_hh = (const float*)d_in[15];
  const float* b_hh = (const float*)d_in[16];
  float* out = (float*)d_out;
  float* wsf = (float*)d_ws;

  unsigned short* QQbf  = (unsigned short*)(wsf + OFF_QQBF);
  unsigned short* KVbf  = (unsigned short*)(wsf + OFF_KVBF);
  unsigned short* aggbf = (unsigned short*)(wsf + OFF_AGGBF);
  unsigned short* msgbf = (unsigned short*)(wsf + OFF_MSGBF);
  unsigned short* x0bf  = (unsigned short*)(wsf + OFF_X0BF);
  int* ip    = (int*)(wsf + OFF_INT);
  int* cntb  = ip;                       // N
  int* curb  = ip + NN;                  // N
  int* bpart = ip + 2 * NN;              // N
  int* baseb = ip + 3 * NN;              // N+1
  int* bsumb = ip + 4 * NN + 1;          // 64
  int2* epairs = (int2*)(ip + 4 * NN + 130);   // 2E ints, 8B aligned
  float* WcatQ  = wsf + OFF_WCATQ;
  float* WcatKV = wsf + OFF_WCATKV;
  float* Wbigb  = wsf + OFF_WBIG;
  float* WgruC  = wsf + OFF_WGRU;
  float* bcatQ  = wsf + OFF_BCATQ;
  float* bcatKV = wsf + OFF_BCATKV;
  float* bgru   = wsf + OFF_BGRU;
  float* bo2    = wsf + OFF_BO2;
  unsigned short* pQ   = (unsigned short*)(wsf + OFF_PQ);
  unsigned short* pKV  = (unsigned short*)(wsf + OFF_PKV);
  unsigned short* pBig = (unsigned short*)(wsf + OFF_PBIG);
  unsigned short* pGRU = (unsigned short*)(wsf + OFF_PGRU);

  // K1: weight prep + zero sort counters
  prep_all<<<871, 256, 0, stream>>>(Wq, bq, Wk, bk, Wv, bv, Wo, bo, W_ih, b_ih,
                                    W_hh, b_hh, WcatQ, bcatQ, WcatKV, bcatKV,
                                    Wbigb, WgruC, bgru, bo2, ip);
  // K2: pack weights + histogram
  pack_hist<<<818, 1024, 0, stream>>>(WcatQ, WcatKV, Wbigb, WgruC,
                                      pQ, pKV, pBig, pGRU, edges, cntb);
  // K3/K4: two-level coalesced scan
  scan_partial<<<49, 1024, 0, stream>>>(cntb, bpart, bsumb);
  scan_final<<<49, 1024, 0, stream>>>(bsumb, bpart, baseb);
  // K5: scatter + projQQ (emits x0bf) + projK1 (emits x1bf into KVbf cols 256+)
  scatter_proj<<<7817, 256, 0, stream>>>(edges, baseb, curb, epairs,
                                         x0, x1, pQ, pKV, bcatQ, bcatKV,
                                         QQbf, KVbf, x0bf);
  // K6: fused attention
  attn_wave_kernel<<<(NN + 3) / 4, 256, 0, stream>>>(edge_attr, QQbf, KVbf,
                                                     baseb, epairs, aggbf);
  // K7: msg = aggbf @ pBig + bo2 (bf16 out)
  gemm_mfma<1, 0, 4, 0><<<dim3(2, MPAD / 64), 256, 0, stream>>>(
      aggbf, pBig, bo2, nullptr, msgbf, nullptr, NN, NN, 512, 128, 128);
  // K8: fused GRU -> out
  gru_fused<<<dim3(4, MPAD / 64), 256, 0, stream>>>(x0bf, msgbf, pGRU, bgru, out);
}

// Round 15
// 378.878 us; speedup vs baseline: 1.2654x; 1.0489x over previous
//
#include <hip/hip_runtime.h>
#include <hip/hip_bf16.h>
#include <math.h>

#define NN 50000
#define EE 800000
#define MPAD 50048          // 64-aligned row pad for MFMA GEMMs

// ---------- workspace layout (offsets in floats) ----------
#define OFF_QQBF   0ull          // MPAD*512 bf16: [QWk_ea h0|h1 | QWk_x1 h0|h1]
#define OFF_X1BF   12900000ull   // MPAD*128 bf16
#define OFF_AGGBF  16200000ull   // MPAD*512 bf16
#define OFF_MSGBF  29100000ull   // MPAD*128 bf16
#define OFF_X0BF   32400000ull   // MPAD*128 bf16
#define OFF_QB     35700000ull   // N*2 fp32 (per-node logit constant)
#define OFF_INT    35900000ull   // ints: 4N+130+2E
#define OFF_WCATQ  37800000ull   // 128*512 fp32
#define OFF_WBIG   37900000ull   // 512*128 fp32
#define OFF_WGRU   38000000ull   // 256*512 fp32
#define OFF_BCATQ  38150000ull   // 512
#define OFF_BGRU   38151000ull   // 512
#define OFF_BO2    38152000ull   // 128 (bo + bv@Wo)
#define OFF_WQB    38153000ull   // 258: wqb[128][2] + qb_const[2]
#define OFF_PQ     38160000ull   // packed bf16
#define OFF_PBIG   38200000ull
#define OFF_PGRU   38240000ull
// end ~38.31M floats = 153 MB

typedef short bf16x8 __attribute__((ext_vector_type(8)));
typedef float f32x4 __attribute__((ext_vector_type(4)));
typedef float fv4 __attribute__((ext_vector_type(4)));

__device__ inline unsigned short f2bf(float f) {   // round-to-nearest-even
  unsigned u = __float_as_uint(f);
  return (unsigned short)((u + 0x7FFFu + ((u >> 16) & 1u)) >> 16);
}
__device__ inline float bf2f(unsigned short u) {
  return __uint_as_float((unsigned)u << 16);
}
__device__ inline float4 bf2f4(ushort4 u) {
  float4 r;
  r.x = bf2f(u.x); r.y = bf2f(u.y); r.z = bf2f(u.z); r.w = bf2f(u.w);
  return r;
}

// ---------- K1: weight prep + sort-counter zeroing: 873 blocks x 256 ----------
__global__ void prep_all(const float* __restrict__ Wq, const float* __restrict__ bq,
                         const float* __restrict__ Wk, const float* __restrict__ bk,
                         const float* __restrict__ Wv, const float* __restrict__ bv,
                         const float* __restrict__ Wo, const float* __restrict__ bo,
                         const float* __restrict__ W_ih, const float* __restrict__ b_ih,
                         const float* __restrict__ W_hh, const float* __restrict__ b_hh,
                         float* __restrict__ WcatQ, float* __restrict__ bcatQ,
                         float* __restrict__ Wbig, float* __restrict__ WgruCat,
                         float* __restrict__ bgru, float* __restrict__ bo2,
                         float* __restrict__ wqb, int* __restrict__ zint) {
  const int bid = blockIdx.x, j = threadIdx.x;
  if (bid < 258) {                       // QWk weights: part0 = ea coef, part1 = x1 coef
    int part = (bid < 129) ? 0 : 1;
    int c0 = (part == 0) ? bid : bid - 129;   // 0..128 (128 => bias row)
    int h = j >> 7, c = j & 127;
    const float* wkrow = Wk + (size_t)(part * 128 + c) * 256 + h * 128;
    float acc = 0.f;
    if (c0 < 128) {
      const float* wqrow = Wq + (size_t)c0 * 256 + h * 128;
      for (int d = 0; d < 128; d++) acc += wqrow[d] * wkrow[d];
      WcatQ[c0 * 512 + part * 256 + j] = acc;
    } else {
      for (int d = 0; d < 128; d++) acc += bq[h * 128 + d] * wkrow[d];
      bcatQ[part * 256 + j] = acc;
    }
  } else if (bid < 514) {                // Wbig (2 rows per block): Wv1Wo | Wv2Wo
    int r = (bid - 258) * 2 + (j >> 7), jj = j & 127;
    int h = (r >> 7) & 1, c = r & 127;
    int srow = (r < 256) ? c : 128 + c;
    float acc = 0.f;
    for (int d = 0; d < 128; d++)
      acc += Wv[(size_t)srow * 256 + h * 128 + d] * Wo[(size_t)(h * 128 + d) * 128 + jj];
    Wbig[r * 128 + jj] = acc;
  } else if (bid < 770) {                // WgruCat row r: [x0|msg] -> [rsum|zsum|i_n|h_n]
    int r = bid - 514;
    for (int c = j; c < 512; c += 256) {
      float v;
      if (r < 128) v = (c < 384) ? W_ih[(size_t)r * 384 + c] : 0.f;
      else {
        int rm = r - 128;
        v = (c < 256) ? W_hh[(size_t)rm * 384 + c]
                      : (c < 384 ? 0.f : W_hh[(size_t)rm * 384 + 256 + (c - 384)]);
      }
      WgruCat[(size_t)r * 512 + c] = v;
    }
  } else if (bid == 770) {               // bgru
    bgru[j] = b_ih[j] + b_hh[j];
    int c1 = j + 256;
    bgru[c1] = (c1 < 384) ? b_ih[c1] : b_hh[c1 - 128];
  } else if (bid == 771) {               // wqb[d][h] = Wq[d,h]·bk_h ; qb_const
    int d = j >> 1, h = j & 1;
    float acc = 0.f;
    for (int t = 0; t < 128; t++) acc += Wq[(size_t)d * 256 + h * 128 + t] * bk[h * 128 + t];
    wqb[j] = acc;
    if (j < 2) {
      float qc = 0.f;
      for (int t = 0; t < 128; t++) qc += bq[j * 128 + t] * bk[j * 128 + t];
      wqb[256 + j] = qc;
    }
  } else if (bid == 772) {               // bo2 = bo + bv@Wo
    if (j < 128) {
      float acc = bo[j];
      for (int t = 0; t < 256; t++) acc += bv[t] * Wo[(size_t)t * 128 + j];
      bo2[j] = acc;
    }
  } else {                               // bid 773..872: zero cnt+cursor (2N ints)
    int g = ((bid - 773) * 256 + j) * 4;
    if (g < 2 * NN) *reinterpret_cast<int4*>(zint + g) = make_int4(0, 0, 0, 0);
  }
}

// ---------- K2: weight pack (blocks 0..31) + edge histogram (32..813) ----------
__global__ __launch_bounds__(1024) void pack_hist(
    const float* __restrict__ WcatQ, const float* __restrict__ Wbig,
    const float* __restrict__ WgruCat,
    unsigned short* __restrict__ pQ, unsigned short* __restrict__ pBig,
    unsigned short* __restrict__ pGRU,
    const int* __restrict__ edges, int* __restrict__ cnt) {
  const int bid = blockIdx.x, tid = threadIdx.x;
  if (bid < 32) {
    int idx = bid * 1024 + tid;          // 0..32767
    const float* W; unsigned short* P; int Nc;
    if (idx < 8192)       { W = WcatQ;   P = pQ;   Nc = 512; }
    else if (idx < 16384) { W = Wbig;    P = pBig; Nc = 128; idx -= 8192; }
    else                  { W = WgruCat; P = pGRU; Nc = 512; idx -= 16384; }
    int nbs = Nc >> 4;
    int lane = idx & 63;
    int pair = idx >> 6;
    int kb = pair / nbs, nb = pair - kb * nbs;
    int kbase = kb * 32 + (lane >> 4) * 8;
    int col = nb * 16 + (lane & 15);
    unsigned short o[8];
#pragma unroll
    for (int j = 0; j < 8; ++j) o[j] = f2bf(W[(size_t)(kbase + j) * Nc + col]);
    *reinterpret_cast<bf16x8*>(P + (size_t)idx * 8) = *reinterpret_cast<bf16x8*>(o);
  } else {
    int e = (bid - 32) * 1024 + tid;
    if (e < EE) atomicAdd(&cnt[edges[EE + e]], 1);
  }
}

// ---------- K3: per-chunk inclusive scan (49 blocks x 1024, coalesced) ----------
__global__ __launch_bounds__(1024) void scan_partial(const int* __restrict__ cnt,
                                                     int* __restrict__ basep,
                                                     int* __restrict__ bsum) {
  __shared__ int sd[1024];
  int t = threadIdx.x, g = blockIdx.x * 1024 + t;
  int v = (g < NN) ? cnt[g] : 0;
  sd[t] = v;
  __syncthreads();
  for (int d = 1; d < 1024; d <<= 1) {
    int add = (t >= d) ? sd[t - d] : 0;
    __syncthreads();
    sd[t] += add;
    __syncthreads();
  }
  if (g < NN) basep[g] = sd[t] - v;
  if (t == 1023) bsum[blockIdx.x] = sd[1023];
}

// ---------- K4: finalize scan ----------
__global__ __launch_bounds__(1024) void scan_final(const int* __restrict__ bsum,
                                                   const int* __restrict__ basep,
                                                   int* __restrict__ base) {
  __shared__ int s_off;
  const int bid = blockIdx.x, tid = threadIdx.x;
  if (tid < 64) {
    int v = (tid < 49) ? bsum[tid] : 0;
    int incl = v;
#pragma unroll
    for (int off = 1; off < 64; off <<= 1) {
      int o = __shfl_up(incl, off);
      if (tid >= off) incl += o;
    }
    int ex = (bid == 0) ? 0 : __shfl(incl, bid - 1);
    if (tid == 0) s_off = ex;
  }
  __syncthreads();
  int g = bid * 1024 + tid;
  if (g < NN) base[g] = basep[g] + s_off;
  if (bid == 48 && tid == 0) base[NN] = EE;
}

// ---------- MFMA bf16 GEMM body ----------
template <int OUT, int AF32, int NF, int EMITA>
__device__ __forceinline__ void gemm_body(
    int bx, int by, const void* __restrict__ Av, const unsigned short* __restrict__ Wp,
    const float* __restrict__ bias, float* __restrict__ C,
    unsigned short* __restrict__ Cbf, unsigned short* __restrict__ Abf,
    int M, int Arows, int K, int Nc, int ldc) {
  const int wid = threadIdx.x >> 6, lane = threadIdx.x & 63;
  const int m0 = by * 64 + wid * 16;
  const int nb0 = bx * NF;
  const int nbs = Nc >> 4;
  const int row = m0 + (lane & 15);
  const int arow = min(row, Arows - 1);
  const int kq = lane >> 4;
  f32x4 acc[NF];
#pragma unroll
  for (int nf = 0; nf < NF; ++nf) acc[nf] = 0.f;
  const int nkb = K >> 5;
  for (int kb = 0; kb < nkb; ++kb) {
    bf16x8 a;
    if (AF32) {
      const float* ap = (const float*)Av + (size_t)arow * K + kb * 32 + kq * 8;
      const float4 f0 = *(const float4*)ap;
      const float4 f1 = *(const float4*)(ap + 4);
      unsigned short t[8] = {f2bf(f0.x), f2bf(f0.y), f2bf(f0.z), f2bf(f0.w),
                             f2bf(f1.x), f2bf(f1.y), f2bf(f1.z), f2bf(f1.w)};
      a = *reinterpret_cast<bf16x8*>(t);
      if (EMITA) {
        if (bx == 0)
          *reinterpret_cast<bf16x8*>(Abf + (size_t)arow * K + kb * 32 + kq * 8) = a;
      }
    } else {
      a = *reinterpret_cast<const bf16x8*>(
          (const unsigned short*)Av + (size_t)arow * K + kb * 32 + kq * 8);
    }
#pragma unroll
    for (int nf = 0; nf < NF; ++nf) {
      bf16x8 b = *reinterpret_cast<const bf16x8*>(
          Wp + ((size_t)(kb * nbs + nb0 + nf) * 64 + lane) * 8);
      acc[nf] = __builtin_amdgcn_mfma_f32_16x16x32_bf16(a, b, acc[nf], 0, 0, 0);
    }
  }
  const int crow0 = m0 + (lane >> 4) * 4;
  const int ccol = lane & 15;
#pragma unroll
  for (int nf = 0; nf < NF; ++nf) {
    const float bv = bias[(nb0 + nf) * 16 + ccol];
#pragma unroll
    for (int r = 0; r < 4; ++r) {
      float v = acc[nf][r] + bv;
      float vp = __shfl_xor(v, 1);
      const int rr = crow0 + r;
      if (rr < M) {
        if (OUT == 2)
          C[(size_t)rr * ldc + (nb0 + nf) * 16 + ccol] = v;
        if (!(lane & 1)) {
          ushort2 o;
          o.x = f2bf(v);
          o.y = f2bf(vp);
          *reinterpret_cast<ushort2*>(Cbf + (size_t)rr * ldc +
                                      (nb0 + nf) * 16 + (ccol & ~1)) = o;
        }
      }
    }
  }
}

template <int OUT, int AF32, int NF, int EMITA>
__global__ __launch_bounds__(256) void gemm_mfma(
    const void* __restrict__ Av, const unsigned short* __restrict__ Wp,
    const float* __restrict__ bias, float* __restrict__ C,
    unsigned short* __restrict__ Cbf, unsigned short* __restrict__ Abf,
    int M, int Arows, int K, int Nc, int ldc) {
  gemm_body<OUT, AF32, NF, EMITA>(blockIdx.x, blockIdx.y, Av, Wp, bias, C, Cbf,
                                  Abf, M, Arows, K, Nc, ldc);
}

// ---------- K5: scatter (0..3124) + projQQ (3125..6252) + x1conv (6253..9380)
//            + qb GEMV (9381..15630) ----------
__global__ __launch_bounds__(256) void scatter_proj(
    const int* __restrict__ edges, const int* __restrict__ base,
    int* __restrict__ cursor, int2* __restrict__ epairs,
    const float* __restrict__ x0, const float* __restrict__ x1,
    const unsigned short* __restrict__ pQ, const float* __restrict__ bcatQ,
    const float* __restrict__ wqb, unsigned short* __restrict__ QQbf,
    unsigned short* __restrict__ x1bf, unsigned short* __restrict__ x0bf,
    float* __restrict__ qb) {
  const int bid = blockIdx.x, tid = threadIdx.x;
  if (bid < 3125) {
    int e = bid * 256 + tid;
    int s = edges[e];
    int d = edges[EE + e];
    int pos = base[d] + atomicAdd(&cursor[d], 1);
    epairs[pos] = make_int2(e, s);
  } else if (bid < 6253) {
    int pb = bid - 3125;
    gemm_body<1, 1, 8, 1>(pb & 3, pb >> 2, x0, pQ, bcatQ, nullptr, QQbf, x0bf,
                          NN, NN, 128, 512, 512);
  } else if (bid < 9381) {
    // x1 -> bf16, zero-pad to MPAD rows
    int i = ((bid - 6253) * 256 + tid) * 8;
    unsigned short o[8];
    if (i + 8 <= NN * 128) {
#pragma unroll
      for (int j = 0; j < 8; ++j) o[j] = f2bf(x1[i + j]);
    } else {
#pragma unroll
      for (int j = 0; j < 8; ++j) o[j] = (i + j < NN * 128) ? f2bf(x1[i + j]) : 0;
    }
    *reinterpret_cast<bf16x8*>(x1bf + i) = *reinterpret_cast<bf16x8*>(o);
  } else {
    // qb[n][h] = x0[n]·wqb[:,h] + qb_const[h]; 8 nodes/block, 32 lanes/node
    int n = (bid - 9381) * 8 + (tid >> 5);
    int l = tid & 31;
    const fv4 x = *(const fv4*)(x0 + (size_t)n * 128 + 4 * l);
    const fv4 wq0 = *(const fv4*)(wqb + 8 * l);
    const fv4 wq1 = *(const fv4*)(wqb + 8 * l + 4);
    float s0 = x.x * wq0.x + x.y * wq0.z + x.z * wq1.x + x.w * wq1.z;
    float s1 = x.x * wq0.y + x.y * wq0.w + x.z * wq1.y + x.w * wq1.w;
#pragma unroll
    for (int off = 16; off; off >>= 1) {
      s0 += __shfl_xor(s0, off);
      s1 += __shfl_xor(s1, off);
    }
    if (l == 0) {
      float2 o;
      o.x = s0 + wqb[256];
      o.y = s1 + wqb[257];
      *(float2*)(qb + (size_t)n * 2) = o;
    }
  }
}

// ---------- K6: fused attention: one wave per node, half-wave per edge ----------
// Per-edge gather: edge_attr (16B/lane fp32) + x1bf (8B/lane) ONLY — K and V both
// folded to x1 via weight products. Logit: ea·w + x1·u + qb[dst]; 12.8 MB x1bf
// working set is L2-resident.
__global__ __launch_bounds__(256) void attn_wave_kernel(
    const float* __restrict__ edge_attr, const unsigned short* __restrict__ QQbf,
    const unsigned short* __restrict__ x1bf, const float* __restrict__ qb,
    const int* __restrict__ base, const int2* __restrict__ epairs,
    unsigned short* __restrict__ aggbf) {
  const int wid = threadIdx.x >> 6, lane = threadIdx.x & 63;
  const int n = blockIdx.x * 4 + wid;
  if (n >= NN) return;
  const int hh = lane >> 5;            // which edge of the pair
  const int l = lane & 31;             // elem group: 4 elems per 128-block
  const unsigned short* qp = QQbf + (size_t)n * 512 + 4 * l;
  const float4 w0 = bf2f4(*(const ushort4*)(qp));        // ea coef h0
  const float4 w1 = bf2f4(*(const ushort4*)(qp + 128));  // ea coef h1
  const float4 u0 = bf2f4(*(const ushort4*)(qp + 256));  // x1 coef h0
  const float4 u1 = bf2f4(*(const ushort4*)(qp + 384));  // x1 coef h1
  const float2 qbv = *(const float2*)(qb + (size_t)n * 2);
  const int beg = base[n], end = base[n + 1];
  float s0 = 0.f, s1 = 0.f;
  float4 ae0 = {0.f, 0.f, 0.f, 0.f}, ae1 = {0.f, 0.f, 0.f, 0.f};
  float4 av0 = {0.f, 0.f, 0.f, 0.f}, av1 = {0.f, 0.f, 0.f, 0.f};
  const float SC = 0.08838834764831845f;
  for (int p = beg; p < end; p += 2) {
    const int pe = min(p + hh, end - 1);
    const bool act = (p + hh < end);
    const int2 es = epairs[pe];
    const fv4 eav = __builtin_nontemporal_load(
        (const fv4*)(edge_attr + (size_t)es.x * 128 + 4 * l));
    const float4 ea = {eav.x, eav.y, eav.z, eav.w};
    const float4 xb = bf2f4(*(const ushort4*)(x1bf + (size_t)es.y * 128 + 4 * l));
    float p0 = ea.x * w0.x + ea.y * w0.y + ea.z * w0.z + ea.w * w0.w
             + xb.x * u0.x + xb.y * u0.y + xb.z * u0.z + xb.w * u0.w;
    float p1 = ea.x * w1.x + ea.y * w1.y + ea.z * w1.z + ea.w * w1.w
             + xb.x * u1.x + xb.y * u1.y + xb.z * u1.z + xb.w * u1.w;
#pragma unroll
    for (int off = 16; off; off >>= 1) {
      p0 += __shfl_xor(p0, off);
      p1 += __shfl_xor(p1, off);
    }
    float a0 = (p0 + qbv.x) * SC; a0 = (a0 < 0.f) ? 0.2f * a0 : a0;
    float a1 = (p1 + qbv.y) * SC; a1 = (a1 < 0.f) ? 0.2f * a1 : a1;
    const float x0 = act ? __expf(a0) : 0.f;
    const float x1 = act ? __expf(a1) : 0.f;
    s0 += x0; s1 += x1;
    ae0.x += x0 * ea.x; ae0.y += x0 * ea.y; ae0.z += x0 * ea.z; ae0.w += x0 * ea.w;
    ae1.x += x1 * ea.x; ae1.y += x1 * ea.y; ae1.z += x1 * ea.z; ae1.w += x1 * ea.w;
    av0.x += x0 * xb.x; av0.y += x0 * xb.y; av0.z += x0 * xb.z; av0.w += x0 * xb.w;
    av1.x += x1 * xb.x; av1.y += x1 * xb.y; av1.z += x1 * xb.z; av1.w += x1 * xb.w;
  }
  // combine the two half-wave accumulators
  s0 += __shfl_xor(s0, 32); s1 += __shfl_xor(s1, 32);
  ae0.x += __shfl_xor(ae0.x, 32); ae0.y += __shfl_xor(ae0.y, 32);
  ae0.z += __shfl_xor(ae0.z, 32); ae0.w += __shfl_xor(ae0.w, 32);
  ae1.x += __shfl_xor(ae1.x, 32); ae1.y += __shfl_xor(ae1.y, 32);
  ae1.z += __shfl_xor(ae1.z, 32); ae1.w += __shfl_xor(ae1.w, 32);
  av0.x += __shfl_xor(av0.x, 32); av0.y += __shfl_xor(av0.y, 32);
  av0.z += __shfl_xor(av0.z, 32); av0.w += __shfl_xor(av0.w, 32);
  av1.x += __shfl_xor(av1.x, 32); av1.y += __shfl_xor(av1.y, 32);
  av1.z += __shfl_xor(av1.z, 32); av1.w += __shfl_xor(av1.w, 32);
  const float i0 = 1.f / (s0 + 1e-16f), i1 = 1.f / (s1 + 1e-16f);
  if (hh == 0) {
    unsigned short* op = aggbf + (size_t)n * 512 + 4 * l;
    ushort4 o;
    o.x = f2bf(ae0.x * i0); o.y = f2bf(ae0.y * i0);
    o.z = f2bf(ae0.z * i0); o.w = f2bf(ae0.w * i0);
    *(ushort4*)op = o;
    o.x = f2bf(ae1.x * i1); o.y = f2bf(ae1.y * i1);
    o.z = f2bf(ae1.z * i1); o.w = f2bf(ae1.w * i1);
    *(ushort4*)(op + 128) = o;
    o.x = f2bf(av0.x * i0); o.y = f2bf(av0.y * i0);
    o.z = f2bf(av0.z * i0); o.w = f2bf(av0.w * i0);
    *(ushort4*)(op + 256) = o;
    o.x = f2bf(av1.x * i1); o.y = f2bf(av1.y * i1);
    o.z = f2bf(av1.z * i1); o.w = f2bf(av1.w * i1);
    *(ushort4*)(op + 384) = o;
  }
}

// ---------- K8: fused GRU: [x0|msg] @ WgruCat -> gates -> out ----------
__global__ __launch_bounds__(256) void gru_fused(
    const unsigned short* __restrict__ x0bf, const unsigned short* __restrict__ msgbf,
    const unsigned short* __restrict__ pGRU, const float* __restrict__ bgru,
    float* __restrict__ out) {
  const int wid = threadIdx.x >> 6, lane = threadIdx.x & 63;
  const int m0 = blockIdx.y * 64 + wid * 16;
  const int xq = blockIdx.x;
  const int row = m0 + (lane & 15);
  const int ar = min(row, NN - 1);
  const int kq = lane >> 4;
  f32x4 acc[4][2];
#pragma unroll
  for (int g = 0; g < 4; ++g)
#pragma unroll
    for (int f = 0; f < 2; ++f) acc[g][f] = 0.f;
  for (int kb = 0; kb < 8; ++kb) {
    bf16x8 a;
    if (kb < 4) {
      a = *reinterpret_cast<const bf16x8*>(x0bf + (size_t)ar * 128 +
                                           kb * 32 + kq * 8);
    } else {
      a = *reinterpret_cast<const bf16x8*>(msgbf + (size_t)ar * 128 +
                                           (kb - 4) * 32 + kq * 8);
    }
#pragma unroll
    for (int g = 0; g < 4; ++g)
#pragma unroll
      for (int f = 0; f < 2; ++f) {
        const int nf = g * 8 + xq * 2 + f;
        bf16x8 b = *reinterpret_cast<const bf16x8*>(
            pGRU + ((size_t)(kb * 32 + nf) * 64 + lane) * 8);
        acc[g][f] = __builtin_amdgcn_mfma_f32_16x16x32_bf16(a, b, acc[g][f], 0, 0, 0);
      }
  }
  const int crow0 = m0 + (lane >> 4) * 4;
  const int ccol = lane & 15;
#pragma unroll
  for (int f = 0; f < 2; ++f) {
    const int d = xq * 32 + f * 16 + ccol;
    const float brs = bgru[d], bzs = bgru[128 + d];
    const float bin = bgru[256 + d], bhn = bgru[384 + d];
#pragma unroll
    for (int r = 0; r < 4; ++r) {
      const int rr = crow0 + r;
      if (rr < NN) {
        const float rs = acc[0][f][r] + brs;
        const float zs = acc[1][f][r] + bzs;
        const float iv = acc[2][f][r] + bin;
        const float hv = acc[3][f][r] + bhn;
        const float rg = 1.f / (1.f + __expf(-rs));
        const float zg = 1.f / (1.f + __expf(-zs));
        const float ng = tanhf(iv + rg * hv);
        const float h = bf2f(msgbf[(size_t)rr * 128 + d]);
        out[(size_t)rr * 128 + d] = (1.f - zg) * ng + zg * h;
      }
    }
  }
}

extern "C" void kernel_launch(void* const* d_in, const int* in_sizes, int n_in,
                              void* d_out, int out_size, void* d_ws, size_t ws_size,
                              hipStream_t stream) {
  const float* x0 = (const float*)d_in[0];
  const float* x1 = (const float*)d_in[1];
  const float* edge_attr = (const float*)d_in[2];
  const int* edges = (const int*)d_in[3];
  const float* Wq = (const float*)d_in[5];
  const float* bq = (const float*)d_in[6];
  const float* Wk = (const float*)d_in[7];
  const float* bk = (const float*)d_in[8];
  const float* Wv = (const float*)d_in[9];
  const float* bv = (const float*)d_in[10];
  const float* Wo = (const float*)d_in[11];
  const float* bo = (const float*)d_in[12];
  const float* W_ih = (const float*)d_in[13];
  const float* b_ih = (const float*)d_in[14];
  const float* W_hh = (const float*)d_in[15];
  const float* b_hh = (const float*)d_in[16];
  float* out = (float*)d_out;
  float* wsf = (float*)d_ws;

  unsigned short* QQbf  = (unsigned short*)(wsf + OFF_QQBF);
  unsigned short* x1bf  = (unsigned short*)(wsf + OFF_X1BF);
  unsigned short* aggbf = (unsigned short*)(wsf + OFF_AGGBF);
  unsigned short* msgbf = (unsigned short*)(wsf + OFF_MSGBF);
  unsigned short* x0bf  = (unsigned short*)(wsf + OFF_X0BF);
  float* qb = wsf + OFF_QB;
  int* ip    = (int*)(wsf + OFF_INT);
  int* cntb  = ip;                       // N
  int* curb  = ip + NN;                  // N
  int* bpart = ip + 2 * NN;              // N
  int* baseb = ip + 3 * NN;              // N+1
  int* bsumb = ip + 4 * NN + 1;          // 64
  int2* epairs = (int2*)(ip + 4 * NN + 130);   // 2E ints, 8B aligned
  float* WcatQ  = wsf + OFF_WCATQ;
  float* Wbigb  = wsf + OFF_WBIG;
  float* WgruC  = wsf + OFF_WGRU;
  float* bcatQ  = wsf + OFF_BCATQ;
  float* bgru   = wsf + OFF_BGRU;
  float* bo2    = wsf + OFF_BO2;
  float* wqb    = wsf + OFF_WQB;
  unsigned short* pQ   = (unsigned short*)(wsf + OFF_PQ);
  unsigned short* pBig = (unsigned short*)(wsf + OFF_PBIG);
  unsigned short* pGRU = (unsigned short*)(wsf + OFF_PGRU);

  // K1: weight prep + zero sort counters
  prep_all<<<873, 256, 0, stream>>>(Wq, bq, Wk, bk, Wv, bv, Wo, bo, W_ih, b_ih,
                                    W_hh, b_hh, WcatQ, bcatQ, Wbigb, WgruC,
                                    bgru, bo2, wqb, ip);
  // K2: pack weights + histogram
  pack_hist<<<814, 1024, 0, stream>>>(WcatQ, Wbigb, WgruC, pQ, pBig, pGRU,
                                      edges, cntb);
  // K3/K4: two-level coalesced scan
  scan_partial<<<49, 1024, 0, stream>>>(cntb, bpart, bsumb);
  scan_final<<<49, 1024, 0, stream>>>(bsumb, bpart, baseb);
  // K5: scatter + projQQ (emits x0bf) + x1->bf16 conv + qb GEMV
  scatter_proj<<<15631, 256, 0, stream>>>(edges, baseb, curb, epairs,
                                          x0, x1, pQ, bcatQ, wqb,
                                          QQbf, x1bf, x0bf, qb);
  // K6: fused attention
  attn_wave_kernel<<<(NN + 3) / 4, 256, 0, stream>>>(edge_attr, QQbf, x1bf, qb,
                                                     baseb, epairs, aggbf);
  // K7: msg = aggbf @ pBig + bo2 (bf16 out)
  gemm_mfma<1, 0, 4, 0><<<dim3(2, MPAD / 64), 256, 0, stream>>>(
      aggbf, pBig, bo2, nullptr, msgbf, nullptr, NN, NN, 512, 128, 128);
  // K8: fused GRU -> out
  gru_fused<<<dim3(4, MPAD / 64), 256, 0, stream>>>(x0bf, msgbf, pGRU, bgru, out);
}